// Round 1
// baseline (95588.953 us; speedup 1.0000x reference)
//
#include <hip/hip_runtime.h>

#define HD 512
#define TILE 16
#define NSTEPS 16
#define NT 256

// M[p][q] = W1[p][q] * sum_i W0[1+i][p] * Wl[q][i]
__global__ void build_M_kernel(const float* __restrict__ W1,
                               const float* __restrict__ W0,
                               const float* __restrict__ Wl,
                               float* __restrict__ M) {
    int idx = blockIdx.x * blockDim.x + threadIdx.x;   // 512*512 total
    int p = idx >> 9;
    int q = idx & 511;
    float c = W0[HD + p]     * Wl[q * 3 + 0]
            + W0[2 * HD + p] * Wl[q * 3 + 1]
            + W0[3 * HD + p] * Wl[q * 3 + 2];
    M[idx] = W1[idx] * c;
}

__global__ __launch_bounds__(NT, 2)
void ode_rk4_kernel(const float* __restrict__ states,
                    const float* __restrict__ W0,
                    const float* __restrict__ b0,
                    const float* __restrict__ W1,
                    const float* __restrict__ b1,
                    const float* __restrict__ Wl,
                    const float* __restrict__ bl,
                    const float* __restrict__ M,
                    float* __restrict__ out) {
    __shared__ float h1s[TILE][HD];          // 32 KB: h1, later h2
    __shared__ float d1s[TILE][HD];          // 32 KB: d1, later F*d2 partial
    __shared__ float xs[TILE][4], xc[TILE][4], ks[TILE][4], ksum[TILE][4];

    const int tid = threadIdx.x;
    const int s0 = blockIdx.x * TILE;
    const float hstp = 1.0f / NSTEPS;

    if (tid < TILE * 4) {
        int s = tid >> 2, c = tid & 3;
        xs[s][c] = states[(s0 + s) * 4 + c];
    }
    __syncthreads();

    for (int step = 0; step < NSTEPS; ++step) {
        float t0 = step * hstp;
        if (tid < TILE * 4) {
            int s = tid >> 2, c = tid & 3;
            xc[s][c] = xs[s][c];
            ksum[s][c] = 0.f;
        }
        __syncthreads();

        for (int stage = 0; stage < 4; ++stage) {
            float tEval = t0 + (stage == 0 ? 0.f : (stage == 3 ? hstp : 0.5f * hstp));

            // ---- phase A: h1 = tanh([t,x] @ W0 + b0), d1 = 1-h1^2 ----
            for (int it = 0; it < TILE * HD / NT; ++it) {
                int idx = it * NT + tid;
                int s = idx >> 9, p = idx & 511;
                float a = b0[p] + tEval * W0[p]
                        + xc[s][0] * W0[HD + p]
                        + xc[s][1] * W0[2 * HD + p]
                        + xc[s][2] * W0[3 * HD + p];
                float hh = tanhf(a);
                h1s[s][p] = hh;
                d1s[s][p] = 1.f - hh * hh;
            }
            __syncthreads();

            // ---- phase B: A2 = H1@W1 ; F = D1@M (thread owns q = tid, tid+256) ----
            float accA0[TILE], accA1[TILE], accF0[TILE], accF1[TILE];
            #pragma unroll
            for (int s = 0; s < TILE; ++s) {
                accA0[s] = 0.f; accA1[s] = 0.f; accF0[s] = 0.f; accF1[s] = 0.f;
            }
            const float* w1p = W1 + tid;
            const float* mp  = M + tid;
            for (int k = 0; k < HD; k += 4) {
                float w1a[4], w1b[4], ma[4], mb[4];
                #pragma unroll
                for (int u = 0; u < 4; ++u) {
                    w1a[u] = w1p[(k + u) * HD];
                    w1b[u] = w1p[(k + u) * HD + 256];
                    ma[u]  = mp[(k + u) * HD];
                    mb[u]  = mp[(k + u) * HD + 256];
                }
                #pragma unroll
                for (int s = 0; s < TILE; ++s) {
                    float4 h4 = *(const float4*)&h1s[s][k];
                    float4 d4 = *(const float4*)&d1s[s][k];
                    accA0[s] += h4.x * w1a[0] + h4.y * w1a[1] + h4.z * w1a[2] + h4.w * w1a[3];
                    accA1[s] += h4.x * w1b[0] + h4.y * w1b[1] + h4.z * w1b[2] + h4.w * w1b[3];
                    accF0[s] += d4.x * ma[0]  + d4.y * ma[1]  + d4.z * ma[2]  + d4.w * ma[3];
                    accF1[s] += d4.x * mb[0]  + d4.y * mb[1]  + d4.z * mb[2]  + d4.w * mb[3];
                }
            }
            __syncthreads();

            // ---- phase C: h2 = tanh(a2+b1); write h2 and (F*d2) back to LDS ----
            {
                float b1q0 = b1[tid], b1q1 = b1[tid + 256];
                #pragma unroll
                for (int s = 0; s < TILE; ++s) {
                    float h2a = tanhf(accA0[s] + b1q0);
                    float h2b = tanhf(accA1[s] + b1q1);
                    float fd = accF0[s] * (1.f - h2a * h2a)
                             + accF1[s] * (1.f - h2b * h2b);
                    h1s[s][tid]       = h2a;
                    h1s[s][tid + 256] = h2b;
                    d1s[s][tid]       = fd;   // trace partial, sum over tid slots 0..255
                }
            }
            __syncthreads();

            // ---- phase D: dz_c = h2 @ Wl[:,c] + bl ; trace = sum(F*d2) ----
            {
                int job = tid >> 2, sub = tid & 3;    // 64 jobs x 4 threads
                int s = job >> 2, c = job & 3;
                float part = 0.f;
                if (c < 3) {
                    int qb = sub * 128;
                    for (int u = 0; u < 128; u += 4) {
                        float4 h4 = *(const float4*)&h1s[s][qb + u];
                        part += h4.x * Wl[(qb + u) * 3 + c]
                              + h4.y * Wl[(qb + u + 1) * 3 + c]
                              + h4.z * Wl[(qb + u + 2) * 3 + c]
                              + h4.w * Wl[(qb + u + 3) * 3 + c];
                    }
                } else {
                    int qb = sub * 64;
                    for (int u = 0; u < 64; u += 4) {
                        float4 f4 = *(const float4*)&d1s[s][qb + u];
                        part += f4.x + f4.y + f4.z + f4.w;
                    }
                }
                part += __shfl_down(part, 2, 64);
                part += __shfl_down(part, 1, 64);
                if (sub == 0) {
                    ks[s][c] = (c < 3) ? (part + bl[c]) : (-part);
                }
            }
            __syncthreads();

            // ---- RK4 combine ----
            if (tid < TILE * 4) {
                int s = tid >> 2, c = tid & 3;
                float kv = ks[s][c];
                float w = (stage == 1 || stage == 2) ? 2.f : 1.f;
                ksum[s][c] += w * kv;
                if (stage < 3) {
                    float a = (stage == 2) ? hstp : 0.5f * hstp;
                    xc[s][c] = xs[s][c] + a * kv;
                } else {
                    xs[s][c] = xs[s][c] + (hstp / 6.f) * ksum[s][c];
                }
            }
            __syncthreads();
        }
    }

    if (tid < TILE * 4) {
        int s = tid >> 2, c = tid & 3;
        out[(s0 + s) * 4 + c] = xs[s][c];
    }
}

extern "C" void kernel_launch(void* const* d_in, const int* in_sizes, int n_in,
                              void* d_out, int out_size, void* d_ws, size_t ws_size,
                              hipStream_t stream) {
    const float* states = (const float*)d_in[0];
    const float* W0 = (const float*)d_in[1];
    const float* b0 = (const float*)d_in[2];
    const float* W1 = (const float*)d_in[3];
    const float* b1 = (const float*)d_in[4];
    const float* Wl = (const float*)d_in[5];
    const float* bl = (const float*)d_in[6];
    float* out = (float*)d_out;
    float* M = (float*)d_ws;   // 512*512 floats = 1 MB

    build_M_kernel<<<(HD * HD) / NT, NT, 0, stream>>>(W1, W0, Wl, M);

    const int B = in_sizes[0] / 4;           // 65536
    ode_rk4_kernel<<<B / TILE, NT, 0, stream>>>(states, W0, b0, W1, b1, Wl, bl, M, out);
}

// Round 3
// 18360.667 us; speedup vs baseline: 5.2062x; 5.2062x over previous
//
#include <hip/hip_runtime.h>
#include <stdint.h>

#define HD 512
#define TILE 64
#define NSTEPS 16
#define NT 512

typedef float f32x16 __attribute__((ext_vector_type(16)));
typedef float f32x4  __attribute__((ext_vector_type(4)));
typedef short s16x8  __attribute__((ext_vector_type(8)));

__device__ __forceinline__ float tanh_fast(float x) {
    // tanh(x) = 1 - 2/(1+e^{2x});  e^{2x} = exp2(x * 2*log2(e))
    float e = __builtin_amdgcn_exp2f(x * 2.885390081777927f);
    return __builtin_fmaf(-2.f, __builtin_amdgcn_rcpf(1.f + e), 1.f);
}

__device__ __forceinline__ uint16_t bf16rne(float f) {
    uint32_t u = __builtin_bit_cast(uint32_t, f);
    return (uint16_t)((u + 0x7fffu + ((u >> 16) & 1u)) >> 16);
}

__device__ __forceinline__ uint32_t bf16pack(float lo, float hi) {
    uint32_t a = __builtin_bit_cast(uint32_t, lo);
    uint32_t b = __builtin_bit_cast(uint32_t, hi);
    a = (a + 0x7fffu + ((a >> 16) & 1u)) >> 16;
    b = (b + 0x7fffu + ((b >> 16) & 1u)) & 0xffff0000u;
    return a | b;
}

// W1T[q][p] = W1[p][q] (bf16);  MT[q][p] = W1[p][q] * sum_i W0[1+i][p]*Wl[q][i] (bf16)
__global__ void prep_kernel(const float* __restrict__ W1,
                            const float* __restrict__ W0,
                            const float* __restrict__ Wl,
                            uint16_t* __restrict__ W1T,
                            uint16_t* __restrict__ MT) {
    int idx = blockIdx.x * 256 + threadIdx.x;   // q*512+p
    int q = idx >> 9, p = idx & 511;
    float w = W1[p * HD + q];
    float c = W0[HD + p]     * Wl[q * 3 + 0]
            + W0[2 * HD + p] * Wl[q * 3 + 1]
            + W0[3 * HD + p] * Wl[q * 3 + 2];
    W1T[idx] = bf16rne(w);
    MT[idx]  = bf16rne(w * c);
}

__global__ __launch_bounds__(NT, 2)
void ode_kernel(const float* __restrict__ states,
                const float* __restrict__ W0,
                const float* __restrict__ b0,
                const float* __restrict__ b1,
                const float* __restrict__ Wl,
                const float* __restrict__ bl,
                const uint16_t* __restrict__ W1T,
                const uint16_t* __restrict__ MT,
                float* __restrict__ out) {
    __shared__ uint16_t h1s[TILE * HD];                       // 64 KB, XOR-swizzled
    __shared__ __align__(16) float xcs[TILE][4];
    __shared__ __align__(16) float xss[TILE][4];
    __shared__ __align__(16) float kss[TILE][4];
    __shared__ __align__(16) float red[TILE][4][4];           // [row][wc][{dz0,dz1,dz2,tr}]

    const int tid  = threadIdx.x;
    const int lane = tid & 63;
    const int wid  = tid >> 6;       // 0..7
    const int wr   = wid >> 2;       // 0..1  row group
    const int wc   = wid & 3;        // 0..3  col group
    const int l31  = lane & 31;
    const int lhi  = lane >> 5;      // 0/1
    const int s0   = blockIdx.x * TILE;

    // ---- persistent preloads ----
    const int pa = (tid & 255) * 2;          // phase-A column pair
    const int shalf = tid >> 8;              // 0/1
    float w0r[8], b0r0, b0r1;
    #pragma unroll
    for (int a = 0; a < 4; ++a) {
        w0r[a * 2]     = W0[a * HD + pa];
        w0r[a * 2 + 1] = W0[a * HD + pa + 1];
    }
    b0r0 = b0[pa]; b0r1 = b0[pa + 1];

    float b1r[4], wlr[4][3];
    const uint16_t* w1p[4];
    const uint16_t* mp[4];
    #pragma unroll
    for (int nt = 0; nt < 4; ++nt) {
        int col = wc * 128 + nt * 32 + l31;
        b1r[nt] = b1[col];
        wlr[nt][0] = Wl[col * 3 + 0];
        wlr[nt][1] = Wl[col * 3 + 1];
        wlr[nt][2] = Wl[col * 3 + 2];
        int off = col * HD + 8 * lhi;
        w1p[nt] = W1T + off;
        mp[nt]  = MT + off;
    }

    if (tid < TILE * 4) {
        int s = tid >> 2, c = tid & 3;
        float v = states[(s0 + s) * 4 + c];
        xss[s][c] = v;
        xcs[s][c] = v;
    }
    __syncthreads();

    const float hstp = 1.f / NSTEPS;
    const int arow = wr * 32 + l31;
    const int abase = arow * HD + 8 * lhi;
    const int aswz = (arow & 7) << 3;

    for (int step = 0; step < NSTEPS; ++step) {
        float t0 = step * hstp;
        for (int stage = 0; stage < 4; ++stage) {
            float tEval = t0 + (stage == 0 ? 0.f : (stage == 3 ? hstp : 0.5f * hstp));

            // ---- phase A: h1 = tanh([t,x]@W0 + b0) -> bf16 LDS (swizzled) ----
            #pragma unroll 4
            for (int it = 0; it < 32; ++it) {
                int s = it * 2 + shalf;
                f32x4 xc = *(const f32x4*)&xcs[s][0];
                float a0 = b0r0 + tEval * w0r[0] + xc.x * w0r[2] + xc.y * w0r[4] + xc.z * w0r[6];
                float a1 = b0r1 + tEval * w0r[1] + xc.x * w0r[3] + xc.y * w0r[5] + xc.z * w0r[7];
                uint32_t pk = bf16pack(tanh_fast(a0), tanh_fast(a1));
                int idx = s * HD + pa;
                ((uint32_t*)h1s)[(idx ^ ((s & 7) << 3)) >> 1] = pk;
            }
            __syncthreads();

            // ---- K-loop: accA = H1@W1 , accF = D1@M  (D1 = 1-H1^2 recomputed) ----
            f32x16 accA[4], accF[4];
            #pragma unroll
            for (int nt = 0; nt < 4; ++nt)
                #pragma unroll
                for (int i = 0; i < 16; ++i) { accA[nt][i] = 0.f; accF[nt][i] = 0.f; }

            #pragma unroll 8
            for (int kk = 0; kk < 32; ++kk) {
                int ai = (abase + kk * 16) ^ aswz;
                union { s16x8 v; uint32_t u[4]; } A, D;
                A.v = *(const s16x8*)(h1s + ai);
                #pragma unroll
                for (int v = 0; v < 4; ++v) {
                    uint32_t w = A.u[v];
                    float flo = __builtin_bit_cast(float, w << 16);
                    float fhi = __builtin_bit_cast(float, w & 0xffff0000u);
                    float dlo = __builtin_fmaf(-flo, flo, 1.f);
                    float dhi = __builtin_fmaf(-fhi, fhi, 1.f);
                    D.u[v] = bf16pack(dlo, dhi);
                }
                #pragma unroll
                for (int nt = 0; nt < 4; ++nt) {
                    s16x8 bw = *(const s16x8*)(w1p[nt] + kk * 16);
                    s16x8 bm = *(const s16x8*)(mp[nt]  + kk * 16);
                    accA[nt] = __builtin_amdgcn_mfma_f32_32x32x16_bf16(A.v, bw, accA[nt], 0, 0, 0);
                    accF[nt] = __builtin_amdgcn_mfma_f32_32x32x16_bf16(D.v, bm, accF[nt], 0, 0, 0);
                }
            }

            // ---- phase C: h2/d2/trace/dz in registers ----
            float dz0[16], dz1[16], dz2[16], fds[16];
            #pragma unroll
            for (int r = 0; r < 16; ++r) { dz0[r] = 0.f; dz1[r] = 0.f; dz2[r] = 0.f; fds[r] = 0.f; }

            #pragma unroll
            for (int nt = 0; nt < 4; ++nt) {
                #pragma unroll
                for (int r = 0; r < 16; ++r) {
                    float a2 = accA[nt][r] + b1r[nt];
                    float h2 = tanh_fast(a2);
                    float d2 = __builtin_fmaf(-h2, h2, 1.f);
                    fds[r] = __builtin_fmaf(accF[nt][r], d2, fds[r]);
                    dz0[r] = __builtin_fmaf(h2, wlr[nt][0], dz0[r]);
                    dz1[r] = __builtin_fmaf(h2, wlr[nt][1], dz1[r]);
                    dz2[r] = __builtin_fmaf(h2, wlr[nt][2], dz2[r]);
                }
            }

            // column reduction across the 32 lanes holding cols of this half
            #pragma unroll
            for (int r = 0; r < 16; ++r) {
                float v0 = dz0[r], v1 = dz1[r], v2 = dz2[r], v3 = fds[r];
                #pragma unroll
                for (int m = 1; m < 32; m <<= 1) {
                    v0 += __shfl_xor(v0, m, 64);
                    v1 += __shfl_xor(v1, m, 64);
                    v2 += __shfl_xor(v2, m, 64);
                    v3 += __shfl_xor(v3, m, 64);
                }
                if (l31 == 0) {
                    int row = wr * 32 + (r & 3) + 8 * (r >> 2) + 4 * lhi;
                    f32x4 o; o.x = v0; o.y = v1; o.z = v2; o.w = v3;
                    *(f32x4*)&red[row][wc][0] = o;
                }
            }
            __syncthreads();

            // ---- combine: k = [dz + bl, -trace]; RK4 update ----
            if (tid < TILE * 4) {
                int s = tid >> 2, c = tid & 3;
                float k = red[s][0][c] + red[s][1][c] + red[s][2][c] + red[s][3][c];
                k = (c < 3) ? (k + bl[c]) : (-k);
                float xsv = xss[s][c];
                if (stage == 0)      { kss[s][c] = k;          xcs[s][c] = xsv + 0.5f * hstp * k; }
                else if (stage == 1) { kss[s][c] += 2.f * k;   xcs[s][c] = xsv + 0.5f * hstp * k; }
                else if (stage == 2) { kss[s][c] += 2.f * k;   xcs[s][c] = xsv + hstp * k; }
                else {
                    float nx = xsv + (hstp / 6.f) * (kss[s][c] + k);
                    xss[s][c] = nx; xcs[s][c] = nx;
                }
            }
            __syncthreads();
        }
    }

    if (tid < TILE * 4) {
        int s = tid >> 2, c = tid & 3;
        out[(s0 + s) * 4 + c] = xss[s][c];
    }
}

extern "C" void kernel_launch(void* const* d_in, const int* in_sizes, int n_in,
                              void* d_out, int out_size, void* d_ws, size_t ws_size,
                              hipStream_t stream) {
    const float* states = (const float*)d_in[0];
    const float* W0 = (const float*)d_in[1];
    const float* b0 = (const float*)d_in[2];
    const float* W1 = (const float*)d_in[3];
    const float* b1 = (const float*)d_in[4];
    const float* Wl = (const float*)d_in[5];
    const float* bl = (const float*)d_in[6];
    float* out = (float*)d_out;

    uint16_t* W1T = (uint16_t*)d_ws;             // 512*512 bf16 = 512 KB
    uint16_t* MT  = W1T + HD * HD;               // +512 KB  (total 1 MB)

    prep_kernel<<<(HD * HD) / 256, 256, 0, stream>>>(W1, W0, Wl, W1T, MT);

    const int B = in_sizes[0] / 4;               // 65536
    ode_kernel<<<B / TILE, NT, 0, stream>>>(states, W0, b0, b1, Wl, bl, W1T, MT, out);
}

// Round 5
// 6061.109 us; speedup vs baseline: 15.7709x; 3.0293x over previous
//
#include <hip/hip_runtime.h>
#include <hip/hip_fp16.h>
#include <stdint.h>

#define HD 512
#define TILE 64
#define NSTEPS 12
#define NT 1024

typedef float    f32x16 __attribute__((ext_vector_type(16)));
typedef float    f32x4  __attribute__((ext_vector_type(4)));
typedef _Float16 f16x8  __attribute__((ext_vector_type(8)));

__device__ __forceinline__ float tanh_fast(float x) {
    float e = __builtin_amdgcn_exp2f(x * 2.885390081777927f);   // e^{2x}
    return __builtin_fmaf(-2.f, __builtin_amdgcn_rcpf(1.f + e), 1.f);
}

// Packed fragment-ordered weights:
//   WP[idx], idx = ((qb*32 + kk)*64 + lane)*8 + j
//   value = W[p][q],  p = kk*16 + (lane>>5)*8 + j,  q = qb*32 + (lane&31)
//   W1P from W1;  MP = W1[p][q] * (sum_i W0[1+i][p] * Wl[q][i])
__global__ void prep_kernel(const float* __restrict__ W1,
                            const float* __restrict__ W0,
                            const float* __restrict__ Wl,
                            __half* __restrict__ W1P,
                            __half* __restrict__ MP) {
    int idx = blockIdx.x * 256 + threadIdx.x;     // 0 .. 512*512-1
    int j    = idx & 7;
    int lane = (idx >> 3) & 63;
    int kk   = (idx >> 9) & 31;
    int qb   = idx >> 14;
    int p = kk * 16 + (lane >> 5) * 8 + j;
    int q = qb * 32 + (lane & 31);
    float w = W1[p * HD + q];
    float c = W0[HD + p]     * Wl[q * 3 + 0]
            + W0[2 * HD + p] * Wl[q * 3 + 1]
            + W0[3 * HD + p] * Wl[q * 3 + 2];
    W1P[idx] = __float2half(w);
    MP[idx]  = __float2half(w * c);
}

union U4 { uint4 q; f16x8 v; __half2 h[4]; uint32_t u[4]; };

__global__ __launch_bounds__(NT)
void ode_kernel(const float* __restrict__ states,
                const float* __restrict__ W0,
                const float* __restrict__ b0,
                const float* __restrict__ b1,
                const float* __restrict__ Wl,
                const float* __restrict__ bl,
                const __half* __restrict__ W1P,
                const __half* __restrict__ MP,
                float* __restrict__ out) {
    __shared__ __half h1s[TILE * HD];                 // 64 KB, swizzled
    __shared__ __align__(16) float red[16][TILE][4];  // 16 KB  [qb][s][{dz0,dz1,dz2,tr}]
    __shared__ __align__(16) float xcs[TILE][4], xss[TILE][4], kss[TILE][4];
    __shared__ float bll[4];

    const int tid  = threadIdx.x;
    const int lane = tid & 63;
    const int wid  = tid >> 6;        // 0..15 = qb
    const int l31  = lane & 31;
    const int lhi  = lane >> 5;       // 0/1
    const int s0   = blockIdx.x * TILE;

    // ---- one-time staging ----
    if (tid < 4) bll[tid] = (tid < 3) ? bl[tid] : 0.f;
    if (tid < TILE * 4) {
        int s = tid >> 2, c = tid & 3;
        float v = states[(s0 + s) * 4 + c];
        xss[s][c] = v;
        xcs[s][c] = v;
    }

    // ---- persistent preloads ----
    const int pa = (tid & 255) * 2;           // phase-A column pair
    const int sg = tid >> 8;                  // 0..3 sample group
    float w0r[8], b0r0, b0r1;
    #pragma unroll
    for (int a = 0; a < 4; ++a) {
        w0r[a * 2]     = W0[a * HD + pa];
        w0r[a * 2 + 1] = W0[a * HD + pa + 1];
    }
    b0r0 = b0[pa]; b0r1 = b0[pa + 1];

    float b1r[16], wl0[16], wl1[16], wl2[16];
    #pragma unroll
    for (int r = 0; r < 16; ++r) {
        int q = wid * 32 + (r & 3) + 8 * (r >> 2) + 4 * lhi;
        b1r[r] = b1[q];
        wl0[r] = Wl[q * 3 + 0];
        wl1[r] = Wl[q * 3 + 1];
        wl2[r] = Wl[q * 3 + 2];
    }

    const __half* w1base = W1P + wid * 16384 + lane * 8;
    const __half* mbase  = MP  + wid * 16384 + lane * 8;

    const int abase = l31 * HD + 8 * lhi;     // h-frag base (half elems), sample = l31
    const int aswz  = (l31 & 7) << 3;

    __syncthreads();

    const float hstp = 1.f / NSTEPS;
    const __half2 one2 = __floats2half2_rn(1.f, 1.f);

    for (int step = 0; step < NSTEPS; ++step) {
        float t0 = step * hstp;
        for (int stage = 0; stage < 4; ++stage) {
            float tEval = t0 + (stage == 0 ? 0.f : (stage == 3 ? hstp : 0.5f * hstp));

            // ---- phase A: h1 = tanh([t,x]@W0 + b0) -> f16 LDS (swizzled) ----
            #pragma unroll 4
            for (int it = 0; it < 16; ++it) {
                int s = it * 4 + sg;
                f32x4 xc = *(const f32x4*)&xcs[s][0];
                float a0 = b0r0 + tEval * w0r[0] + xc.x * w0r[2] + xc.y * w0r[4] + xc.z * w0r[6];
                float a1 = b0r1 + tEval * w0r[1] + xc.x * w0r[3] + xc.y * w0r[5] + xc.z * w0r[7];
                uint32_t pk = __builtin_bit_cast(uint32_t,
                    __builtin_amdgcn_cvt_pkrtz(tanh_fast(a0), tanh_fast(a1)));
                int elem = s * HD + pa;
                ((uint32_t*)h1s)[((elem ^ ((s & 7) << 3)) >> 1)] = pk;
            }
            __syncthreads();

            // ---- K-loop: accA[sf] = W1^T @ H1^T, accF[sf] = M^T @ D1^T ----
            f32x16 accA0 = {}, accA1 = {}, accF0 = {}, accF1 = {};
            U4 wa, wm;
            wa.q = *(const uint4*)(w1base);
            wm.q = *(const uint4*)(mbase);
            #pragma unroll 4
            for (int kk = 0; kk < 32; ++kk) {
                U4 wa_c = wa, wm_c = wm;
                if (kk < 31) {
                    wa.q = *(const uint4*)(w1base + (kk + 1) * 512);
                    wm.q = *(const uint4*)(mbase  + (kk + 1) * 512);
                }
                int a0 = (abase + kk * 16) ^ aswz;
                U4 H0, H1, D0, D1;
                H0.q = *(const uint4*)(h1s + a0);
                H1.q = *(const uint4*)(h1s + a0 + 32 * HD);
                #pragma unroll
                for (int i = 0; i < 4; ++i) {
                    D0.h[i] = __hfma2(__hneg2(H0.h[i]), H0.h[i], one2);   // 1 - h^2
                    D1.h[i] = __hfma2(__hneg2(H1.h[i]), H1.h[i], one2);
                }
                accA0 = __builtin_amdgcn_mfma_f32_32x32x16_f16(wa_c.v, H0.v, accA0, 0, 0, 0);
                accF0 = __builtin_amdgcn_mfma_f32_32x32x16_f16(wm_c.v, D0.v, accF0, 0, 0, 0);
                accA1 = __builtin_amdgcn_mfma_f32_32x32x16_f16(wa_c.v, H1.v, accA1, 0, 0, 0);
                accF1 = __builtin_amdgcn_mfma_f32_32x32x16_f16(wm_c.v, D1.v, accF1, 0, 0, 0);
            }

            // ---- phase C: h2/d2 per q-row; in-lane q-reduction ----
            float dzA0 = 0.f, dzA1 = 0.f, dzA2 = 0.f, fdA = 0.f;   // sf0
            float dzB0 = 0.f, dzB1 = 0.f, dzB2 = 0.f, fdB = 0.f;   // sf1
            #pragma unroll
            for (int r = 0; r < 16; ++r) {
                float h2a = tanh_fast(accA0[r] + b1r[r]);
                float h2b = tanh_fast(accA1[r] + b1r[r]);
                float d2a = __builtin_fmaf(-h2a, h2a, 1.f);
                float d2b = __builtin_fmaf(-h2b, h2b, 1.f);
                fdA  = __builtin_fmaf(accF0[r], d2a, fdA);
                fdB  = __builtin_fmaf(accF1[r], d2b, fdB);
                dzA0 = __builtin_fmaf(h2a, wl0[r], dzA0);
                dzA1 = __builtin_fmaf(h2a, wl1[r], dzA1);
                dzA2 = __builtin_fmaf(h2a, wl2[r], dzA2);
                dzB0 = __builtin_fmaf(h2b, wl0[r], dzB0);
                dzB1 = __builtin_fmaf(h2b, wl1[r], dzB1);
                dzB2 = __builtin_fmaf(h2b, wl2[r], dzB2);
            }
            // combine q-halves across lane^32
            dzA0 += __shfl_xor(dzA0, 32, 64);  dzB0 += __shfl_xor(dzB0, 32, 64);
            dzA1 += __shfl_xor(dzA1, 32, 64);  dzB1 += __shfl_xor(dzB1, 32, 64);
            dzA2 += __shfl_xor(dzA2, 32, 64);  dzB2 += __shfl_xor(dzB2, 32, 64);
            fdA  += __shfl_xor(fdA, 32, 64);   fdB  += __shfl_xor(fdB, 32, 64);

            {   // lhi=0 lanes write sample l31 (sf0); lhi=1 lanes write 32+l31 (sf1)
                int s_w = lhi * 32 + l31;
                f32x4 o;
                o.x = lhi ? dzB0 : dzA0;
                o.y = lhi ? dzB1 : dzA1;
                o.z = lhi ? dzB2 : dzA2;
                o.w = lhi ? fdB  : fdA;
                *(f32x4*)&red[wid][s_w][0] = o;
            }
            __syncthreads();

            // ---- combine: k = [dz + bl, -trace]; RK4 update ----
            if (tid < TILE * 4) {
                int s = tid >> 2, c = tid & 3;
                float k = 0.f;
                #pragma unroll
                for (int qb = 0; qb < 16; ++qb) k += red[qb][s][c];
                k = (c < 3) ? (k + bll[c]) : (-k);
                float xsv = xss[s][c];
                if (stage == 0)      { kss[s][c] = k;          xcs[s][c] = xsv + 0.5f * hstp * k; }
                else if (stage == 1) { kss[s][c] += 2.f * k;   xcs[s][c] = xsv + 0.5f * hstp * k; }
                else if (stage == 2) { kss[s][c] += 2.f * k;   xcs[s][c] = xsv + hstp * k; }
                else {
                    float nx = xsv + (hstp / 6.f) * (kss[s][c] + k);
                    xss[s][c] = nx; xcs[s][c] = nx;
                }
            }
            __syncthreads();
        }
    }

    if (tid < TILE * 4) {
        int s = tid >> 2, c = tid & 3;
        out[(s0 + s) * 4 + c] = xss[s][c];
    }
}

extern "C" void kernel_launch(void* const* d_in, const int* in_sizes, int n_in,
                              void* d_out, int out_size, void* d_ws, size_t ws_size,
                              hipStream_t stream) {
    const float* states = (const float*)d_in[0];
    const float* W0 = (const float*)d_in[1];
    const float* b0 = (const float*)d_in[2];
    const float* W1 = (const float*)d_in[3];
    const float* b1 = (const float*)d_in[4];
    const float* Wl = (const float*)d_in[5];
    const float* bl = (const float*)d_in[6];
    float* out = (float*)d_out;

    __half* W1P = (__half*)d_ws;                 // 512*512 f16 = 512 KB
    __half* MP  = W1P + HD * HD;                 // +512 KB (total 1 MB)

    prep_kernel<<<(HD * HD) / 256, 256, 0, stream>>>(W1, W0, Wl, W1P, MP);

    const int B = in_sizes[0] / 4;               // 65536
    ode_kernel<<<B / TILE, NT, 0, stream>>>(states, W0, b0, b1, Wl, bl, W1P, MP, out);
}

// Round 6
// 3077.071 us; speedup vs baseline: 31.0649x; 1.9698x over previous
//
#include <hip/hip_runtime.h>
#include <hip/hip_fp16.h>
#include <stdint.h>

#define HD 512
#define TILE 64
#define NSTEPS 8
#define NT 1024

typedef float    f32x16 __attribute__((ext_vector_type(16)));
typedef float    f32x4  __attribute__((ext_vector_type(4)));
typedef _Float16 f16x8  __attribute__((ext_vector_type(8)));

typedef __attribute__((address_space(3))) uint32_t lds_u32;
typedef __attribute__((address_space(1))) const uint32_t glb_u32;

__device__ __forceinline__ float tanh_fast(float x) {
    float e = __builtin_amdgcn_exp2f(x * 2.885390081777927f);   // e^{2x}
    return __builtin_fmaf(-2.f, __builtin_amdgcn_rcpf(1.f + e), 1.f);
}

// Packed fragment-ordered weights:
//   WP[idx], idx = ((qb*32 + kk)*64 + lane)*8 + j
//   value = W[p][q],  p = kk*16 + (lane>>5)*8 + j,  q = qb*32 + (lane&31)
__global__ void prep_kernel(const float* __restrict__ W1,
                            const float* __restrict__ W0,
                            const float* __restrict__ Wl,
                            __half* __restrict__ W1P,
                            __half* __restrict__ MP) {
    int idx = blockIdx.x * 256 + threadIdx.x;     // 0 .. 512*512-1
    int j    = idx & 7;
    int lane = (idx >> 3) & 63;
    int kk   = (idx >> 9) & 31;
    int qb   = idx >> 14;
    int p = kk * 16 + (lane >> 5) * 8 + j;
    int q = qb * 32 + (lane & 31);
    float w = W1[p * HD + q];
    float c = W0[HD + p]     * Wl[q * 3 + 0]
            + W0[2 * HD + p] * Wl[q * 3 + 1]
            + W0[3 * HD + p] * Wl[q * 3 + 2];
    W1P[idx] = __float2half(w);
    MP[idx]  = __float2half(w * c);
}

union U4 { uint4 q; f16x8 v; __half2 h[4]; uint32_t u[4]; };

__global__ __launch_bounds__(NT, 4)
void ode_kernel(const float* __restrict__ states,
                const float* __restrict__ W0,
                const float* __restrict__ b0,
                const float* __restrict__ b1,
                const float* __restrict__ Wl,
                const float* __restrict__ bl,
                const __half* __restrict__ W1P,
                const __half* __restrict__ MP,
                float* __restrict__ out) {
    __shared__ __half   h1s[TILE * HD];                 // 64 KB, swizzled
    __shared__ uint8_t  wbuf[2][16][2][1024];           // 64 KB weight DMA ring
    __shared__ __align__(16) float red[16][TILE][4];    // 16 KB [qb][s][{dz0,dz1,dz2,tr}]
    __shared__ __align__(16) float wlb[HD][4];          // 8 KB  {Wl0,Wl1,Wl2,b1}
    __shared__ __align__(16) float xcs[TILE][4], xss[TILE][4], kss[TILE][4];
    __shared__ float bll[4];

    const int tid  = threadIdx.x;
    const int lane = tid & 63;
    const int wid  = tid >> 6;        // 0..15 = qb
    const int l31  = lane & 31;
    const int lhi  = lane >> 5;       // 0/1
    const int s0   = blockIdx.x * TILE;

    // ---- one-time staging ----
    if (tid < 4) bll[tid] = (tid < 3) ? bl[tid] : 0.f;
    if (tid < HD) {
        f32x4 w;
        w.x = Wl[tid * 3 + 0]; w.y = Wl[tid * 3 + 1]; w.z = Wl[tid * 3 + 2];
        w.w = b1[tid];
        *(f32x4*)&wlb[tid][0] = w;
    }
    if (tid < TILE * 4) {
        int s = tid >> 2, c = tid & 3;
        float v = states[(s0 + s) * 4 + c];
        xss[s][c] = v;
        xcs[s][c] = v;
    }

    // ---- persistent preloads ----
    const int pa = (tid & 255) * 2;           // phase-A column pair
    const int sg = tid >> 8;                  // 0..3 sample group
    float w0r[8], b0r0, b0r1;
    #pragma unroll
    for (int a = 0; a < 4; ++a) {
        w0r[a * 2]     = W0[a * HD + pa];
        w0r[a * 2 + 1] = W0[a * HD + pa + 1];
    }
    b0r0 = b0[pa]; b0r1 = b0[pa + 1];

    // weight DMA sources (per-lane) and LDS ring bases (wave-uniform)
    const __half* w1src = W1P + wid * 16384 + lane * 8;
    const __half* msrc  = MP  + wid * 16384 + lane * 8;
    uint8_t* wb0 = &wbuf[0][wid][0][0];

    // prologue: slice 0 -> buf0, slice 1 -> buf1
    {
        __builtin_amdgcn_global_load_lds((glb_u32*)(w1src), (lds_u32*)(uintptr_t)(wb0), 16, 0, 0);
        __builtin_amdgcn_global_load_lds((glb_u32*)(msrc), (lds_u32*)(uintptr_t)(wb0 + 1024), 16, 0, 0);
        __builtin_amdgcn_global_load_lds((glb_u32*)(w1src + 512), (lds_u32*)(uintptr_t)(wb0 + 32768), 16, 0, 0);
        __builtin_amdgcn_global_load_lds((glb_u32*)(msrc + 512), (lds_u32*)(uintptr_t)(wb0 + 32768 + 1024), 16, 0, 0);
    }

    const int abase = l31 * HD + 8 * lhi;     // H-frag base (half elems), sample = l31
    const int aswz  = (l31 & 7) << 3;
    const int wlbase = (wid * 32 + 4 * lhi);  // q base for phase C

    __syncthreads();

    const float hstp = 1.f / NSTEPS;
    const __half2 one2 = __floats2half2_rn(1.f, 1.f);

    for (int step = 0; step < NSTEPS; ++step) {
        float t0 = step * hstp;
        for (int stage = 0; stage < 4; ++stage) {
            float tEval = t0 + (stage == 0 ? 0.f : (stage == 3 ? hstp : 0.5f * hstp));

            // ---- phase A: h1 = tanh([t,x]@W0 + b0) -> f16 LDS (swizzled) ----
            #pragma unroll 4
            for (int it = 0; it < 16; ++it) {
                int s = it * 4 + sg;
                f32x4 xc = *(const f32x4*)&xcs[s][0];
                float a0 = b0r0 + tEval * w0r[0] + xc.x * w0r[2] + xc.y * w0r[4] + xc.z * w0r[6];
                float a1 = b0r1 + tEval * w0r[1] + xc.x * w0r[3] + xc.y * w0r[5] + xc.z * w0r[7];
                uint32_t pk = __builtin_bit_cast(uint32_t,
                    __builtin_amdgcn_cvt_pkrtz(tanh_fast(a0), tanh_fast(a1)));
                int elem = s * HD + pa;
                ((uint32_t*)h1s)[((elem ^ ((s & 7) << 3)) >> 1)] = pk;
            }
            __syncthreads();

            // ---- K-loop: accA = W1^T@H^T, accF = M^T@D^T; weights via LDS DMA ring ----
            f32x16 accA0 = {}, accA1 = {}, accF0 = {}, accF1 = {};

            #pragma unroll 4
            for (int kk = 0; kk < 32; ++kk) {
                const int buf = kk & 1;
                uint8_t* wbase = wb0 + buf * 32768;

                // slice kk resident when outstanding <= 2 (slice kk+1 in flight)
                asm volatile("s_waitcnt vmcnt(2)" ::: "memory");
                __builtin_amdgcn_sched_barrier(0);

                U4 wa, wm, H0, H1, D0, D1;
                wa.q = *(const uint4*)(wbase + lane * 16);
                wm.q = *(const uint4*)(wbase + 1024 + lane * 16);
                int a0 = (abase + kk * 16) ^ aswz;
                H0.q = *(const uint4*)(h1s + a0);
                H1.q = *(const uint4*)(h1s + a0 + 32 * HD);

                // ds_reads retired -> safe to overwrite this buf with slice kk+2
                asm volatile("s_waitcnt lgkmcnt(0)" ::: "memory");
                __builtin_amdgcn_sched_barrier(0);
                {
                    int nk = (kk + 2) & 31;
                    __builtin_amdgcn_global_load_lds((glb_u32*)(w1src + nk * 512),
                        (lds_u32*)(uintptr_t)(wbase), 16, 0, 0);
                    __builtin_amdgcn_global_load_lds((glb_u32*)(msrc + nk * 512),
                        (lds_u32*)(uintptr_t)(wbase + 1024), 16, 0, 0);
                }

                #pragma unroll
                for (int i = 0; i < 4; ++i) {
                    D0.h[i] = __hfma2(__hneg2(H0.h[i]), H0.h[i], one2);   // 1 - h^2
                    D1.h[i] = __hfma2(__hneg2(H1.h[i]), H1.h[i], one2);
                }
                __builtin_amdgcn_s_setprio(1);
                accA0 = __builtin_amdgcn_mfma_f32_32x32x16_f16(wa.v, H0.v, accA0, 0, 0, 0);
                accF0 = __builtin_amdgcn_mfma_f32_32x32x16_f16(wm.v, D0.v, accF0, 0, 0, 0);
                accA1 = __builtin_amdgcn_mfma_f32_32x32x16_f16(wa.v, H1.v, accA1, 0, 0, 0);
                accF1 = __builtin_amdgcn_mfma_f32_32x32x16_f16(wm.v, D1.v, accF1, 0, 0, 0);
                __builtin_amdgcn_s_setprio(0);
            }

            // ---- phase C: h2/d2 per q-row; in-lane q-reduction ----
            float dzA0 = 0.f, dzA1 = 0.f, dzA2 = 0.f, fdA = 0.f;   // sf0
            float dzB0 = 0.f, dzB1 = 0.f, dzB2 = 0.f, fdB = 0.f;   // sf1
            #pragma unroll
            for (int r = 0; r < 16; ++r) {
                f32x4 w = *(const f32x4*)&wlb[wlbase + (r & 3) + 8 * (r >> 2)][0];
                float h2a = tanh_fast(accA0[r] + w.w);
                float h2b = tanh_fast(accA1[r] + w.w);
                float d2a = __builtin_fmaf(-h2a, h2a, 1.f);
                float d2b = __builtin_fmaf(-h2b, h2b, 1.f);
                fdA  = __builtin_fmaf(accF0[r], d2a, fdA);
                fdB  = __builtin_fmaf(accF1[r], d2b, fdB);
                dzA0 = __builtin_fmaf(h2a, w.x, dzA0);
                dzA1 = __builtin_fmaf(h2a, w.y, dzA1);
                dzA2 = __builtin_fmaf(h2a, w.z, dzA2);
                dzB0 = __builtin_fmaf(h2b, w.x, dzB0);
                dzB1 = __builtin_fmaf(h2b, w.y, dzB1);
                dzB2 = __builtin_fmaf(h2b, w.z, dzB2);
            }
            // combine q-halves across lane^32
            dzA0 += __shfl_xor(dzA0, 32, 64);  dzB0 += __shfl_xor(dzB0, 32, 64);
            dzA1 += __shfl_xor(dzA1, 32, 64);  dzB1 += __shfl_xor(dzB1, 32, 64);
            dzA2 += __shfl_xor(dzA2, 32, 64);  dzB2 += __shfl_xor(dzB2, 32, 64);
            fdA  += __shfl_xor(fdA, 32, 64);   fdB  += __shfl_xor(fdB, 32, 64);

            {   // lhi=0 lanes write sample l31 (sf0); lhi=1 lanes write 32+l31 (sf1)
                int s_w = lhi * 32 + l31;
                f32x4 o;
                o.x = lhi ? dzB0 : dzA0;
                o.y = lhi ? dzB1 : dzA1;
                o.z = lhi ? dzB2 : dzA2;
                o.w = lhi ? fdB  : fdA;
                *(f32x4*)&red[wid][s_w][0] = o;
            }
            __syncthreads();

            // ---- combine: k = [dz + bl, -trace]; RK4 update ----
            if (tid < TILE * 4) {
                int s = tid >> 2, c = tid & 3;
                float k = 0.f;
                #pragma unroll
                for (int qb = 0; qb < 16; ++qb) k += red[qb][s][c];
                k = (c < 3) ? (k + bll[c]) : (-k);
                float xsv = xss[s][c];
                if (stage == 0)      { kss[s][c] = k;          xcs[s][c] = xsv + 0.5f * hstp * k; }
                else if (stage == 1) { kss[s][c] += 2.f * k;   xcs[s][c] = xsv + 0.5f * hstp * k; }
                else if (stage == 2) { kss[s][c] += 2.f * k;   xcs[s][c] = xsv + hstp * k; }
                else {
                    float nx = xsv + (hstp / 6.f) * (kss[s][c] + k);
                    xss[s][c] = nx; xcs[s][c] = nx;
                }
            }
            __syncthreads();
        }
    }

    if (tid < TILE * 4) {
        int s = tid >> 2, c = tid & 3;
        out[(s0 + s) * 4 + c] = xss[s][c];
    }
}

extern "C" void kernel_launch(void* const* d_in, const int* in_sizes, int n_in,
                              void* d_out, int out_size, void* d_ws, size_t ws_size,
                              hipStream_t stream) {
    const float* states = (const float*)d_in[0];
    const float* W0 = (const float*)d_in[1];
    const float* b0 = (const float*)d_in[2];
    const float* W1 = (const float*)d_in[3];
    const float* b1 = (const float*)d_in[4];
    const float* Wl = (const float*)d_in[5];
    const float* bl = (const float*)d_in[6];
    float* out = (float*)d_out;

    __half* W1P = (__half*)d_ws;                 // 512*512 f16 = 512 KB
    __half* MP  = W1P + HD * HD;                 // +512 KB (total 1 MB)

    prep_kernel<<<(HD * HD) / 256, 256, 0, stream>>>(W1, W0, Wl, W1P, MP);

    const int B = in_sizes[0] / 4;               // 65536
    ode_kernel<<<B / TILE, NT, 0, stream>>>(states, W0, b0, b1, Wl, bl, W1P, MP, out);
}

// Round 7
// 2322.227 us; speedup vs baseline: 41.1626x; 1.3251x over previous
//
#include <hip/hip_runtime.h>
#include <hip/hip_fp16.h>
#include <stdint.h>

#define HD 512
#define TILE 64
#define NSTEPS 6
#define NT 1024

typedef float    f32x16 __attribute__((ext_vector_type(16)));
typedef float    f32x4  __attribute__((ext_vector_type(4)));
typedef _Float16 f16x8  __attribute__((ext_vector_type(8)));

typedef __attribute__((address_space(3))) uint32_t lds_u32;
typedef __attribute__((address_space(1))) const uint32_t glb_u32;

__device__ __forceinline__ float tanh_fast(float x) {
    float e = __builtin_amdgcn_exp2f(x * 2.885390081777927f);   // e^{2x}
    return __builtin_fmaf(-2.f, __builtin_amdgcn_rcpf(1.f + e), 1.f);
}

// Packed fragment-ordered weights:
//   WP[idx], idx = ((qb*32 + kk)*64 + lane)*8 + j
//   value = W[p][q],  p = kk*16 + (lane>>5)*8 + j,  q = qb*32 + (lane&31)
__global__ void prep_kernel(const float* __restrict__ W1,
                            const float* __restrict__ W0,
                            const float* __restrict__ Wl,
                            __half* __restrict__ W1P,
                            __half* __restrict__ MP) {
    int idx = blockIdx.x * 256 + threadIdx.x;     // 0 .. 512*512-1
    int j    = idx & 7;
    int lane = (idx >> 3) & 63;
    int kk   = (idx >> 9) & 31;
    int qb   = idx >> 14;
    int p = kk * 16 + (lane >> 5) * 8 + j;
    int q = qb * 32 + (lane & 31);
    float w = W1[p * HD + q];
    float c = W0[HD + p]     * Wl[q * 3 + 0]
            + W0[2 * HD + p] * Wl[q * 3 + 1]
            + W0[3 * HD + p] * Wl[q * 3 + 2];
    W1P[idx] = __float2half(w);
    MP[idx]  = __float2half(w * c);
}

union U4 { uint4 q; f16x8 v; __half2 h[4]; uint32_t u[4]; };

__global__ __launch_bounds__(NT, 4)
void ode_kernel(const float* __restrict__ states,
                const float* __restrict__ W0,
                const float* __restrict__ b0,
                const float* __restrict__ b1,
                const float* __restrict__ Wl,
                const float* __restrict__ bl,
                const __half* __restrict__ W1P,
                const __half* __restrict__ MP,
                float* __restrict__ out) {
    __shared__ __half   h1s[TILE * HD];                 // 64 KB, 16-row swizzled
    __shared__ uint8_t  wbuf[2][16][2][1024];           // 64 KB weight DMA ring
    __shared__ __align__(16) float red[16][TILE][4];    // 16 KB [qb][s][{dz0,dz1,dz2,tr}]
    __shared__ __align__(16) float wlb[HD][4];          // 8 KB  {Wl0,Wl1,Wl2,b1}
    __shared__ __align__(16) float xcs[TILE][4], xss[TILE][4], kss[TILE][4];
    __shared__ float bll[4];

    const int tid  = threadIdx.x;
    const int lane = tid & 63;
    const int wid  = tid >> 6;        // 0..15 = qb
    const int l31  = lane & 31;
    const int lhi  = lane >> 5;       // 0/1
    const int s0   = blockIdx.x * TILE;

    // ---- one-time staging ----
    if (tid < 4) bll[tid] = (tid < 3) ? bl[tid] : 0.f;
    if (tid < HD) {
        f32x4 w;
        w.x = Wl[tid * 3 + 0]; w.y = Wl[tid * 3 + 1]; w.z = Wl[tid * 3 + 2];
        w.w = b1[tid];
        *(f32x4*)&wlb[tid][0] = w;
    }
    if (tid < TILE * 4) {
        int s = tid >> 2, c = tid & 3;
        float v = states[(s0 + s) * 4 + c];
        xss[s][c] = v;
        xcs[s][c] = v;
    }

    // ---- persistent preloads ----
    const int pa = (tid & 255) * 2;           // phase-A column pair
    const int sg = tid >> 8;                  // 0..3 sample group
    float w0r[8], b0r0, b0r1;
    #pragma unroll
    for (int a = 0; a < 4; ++a) {
        w0r[a * 2]     = W0[a * HD + pa];
        w0r[a * 2 + 1] = W0[a * HD + pa + 1];
    }
    b0r0 = b0[pa]; b0r1 = b0[pa + 1];

    // weight DMA sources (per-lane) and LDS ring bases (wave-uniform)
    const __half* w1src = W1P + wid * 16384 + lane * 8;
    const __half* msrc  = MP  + wid * 16384 + lane * 8;
    uint8_t* wb0 = &wbuf[0][wid][0][0];

    // prologue: slice 0 -> buf0, slice 1 -> buf1
    {
        __builtin_amdgcn_global_load_lds((glb_u32*)(w1src), (lds_u32*)(uintptr_t)(wb0), 16, 0, 0);
        __builtin_amdgcn_global_load_lds((glb_u32*)(msrc), (lds_u32*)(uintptr_t)(wb0 + 1024), 16, 0, 0);
        __builtin_amdgcn_global_load_lds((glb_u32*)(w1src + 512), (lds_u32*)(uintptr_t)(wb0 + 32768), 16, 0, 0);
        __builtin_amdgcn_global_load_lds((glb_u32*)(msrc + 512), (lds_u32*)(uintptr_t)(wb0 + 32768 + 1024), 16, 0, 0);
    }

    const int abase = l31 * HD + 8 * lhi;     // H-frag base (half elems), sample = l31
    const int aswz  = (l31 & 15) << 3;        // 16-row XOR swizzle (2-way max)
    const int wlbase = (wid * 32 + 4 * lhi);  // q base for phase C

    __syncthreads();

    const float hstp = 1.f / NSTEPS;
    const __half2 one2 = __floats2half2_rn(1.f, 1.f);

    for (int step = 0; step < NSTEPS; ++step) {
        float t0 = step * hstp;
        for (int stage = 0; stage < 4; ++stage) {
            float tEval = t0 + (stage == 0 ? 0.f : (stage == 3 ? hstp : 0.5f * hstp));

            // ---- phase A: h1 = tanh([t,x]@W0 + b0) -> f16 LDS (swizzled) ----
            #pragma unroll 4
            for (int it = 0; it < 16; ++it) {
                int s = it * 4 + sg;
                f32x4 xc = *(const f32x4*)&xcs[s][0];
                float a0 = b0r0 + tEval * w0r[0] + xc.x * w0r[2] + xc.y * w0r[4] + xc.z * w0r[6];
                float a1 = b0r1 + tEval * w0r[1] + xc.x * w0r[3] + xc.y * w0r[5] + xc.z * w0r[7];
                uint32_t pk = __builtin_bit_cast(uint32_t,
                    __builtin_amdgcn_cvt_pkrtz(tanh_fast(a0), tanh_fast(a1)));
                int elem = s * HD + pa;
                ((uint32_t*)h1s)[((elem ^ ((s & 15) << 3)) >> 1)] = pk;
            }
            __syncthreads();

            // ---- K-loop: accA = W1^T@H^T, accF = M^T@D^T; weights via LDS DMA ring ----
            f32x16 accA0 = {}, accA1 = {}, accF0 = {}, accF1 = {};

            #pragma unroll 4
            for (int kk = 0; kk < 32; ++kk) {
                const int buf = kk & 1;
                uint8_t* wbase = wb0 + buf * 32768;

                // slice kk resident when outstanding <= 2 (slice kk+1 in flight)
                asm volatile("s_waitcnt vmcnt(2)" ::: "memory");
                __builtin_amdgcn_sched_barrier(0);

                U4 wa, wm, H0, H1, D0, D1;
                wa.q = *(const uint4*)(wbase + lane * 16);
                wm.q = *(const uint4*)(wbase + 1024 + lane * 16);
                int a0 = (abase + kk * 16) ^ aswz;
                H0.q = *(const uint4*)(h1s + a0);
                H1.q = *(const uint4*)(h1s + a0 + 32 * HD);

                // ds_reads retired -> safe to overwrite this buf with slice kk+2
                asm volatile("s_waitcnt lgkmcnt(0)" ::: "memory");
                __builtin_amdgcn_sched_barrier(0);
                {
                    int nk = (kk + 2) & 31;
                    __builtin_amdgcn_global_load_lds((glb_u32*)(w1src + nk * 512),
                        (lds_u32*)(uintptr_t)(wbase), 16, 0, 0);
                    __builtin_amdgcn_global_load_lds((glb_u32*)(msrc + nk * 512),
                        (lds_u32*)(uintptr_t)(wbase + 1024), 16, 0, 0);
                }

                #pragma unroll
                for (int i = 0; i < 4; ++i) {
                    D0.h[i] = __hfma2(__hneg2(H0.h[i]), H0.h[i], one2);   // 1 - h^2
                    D1.h[i] = __hfma2(__hneg2(H1.h[i]), H1.h[i], one2);
                }
                __builtin_amdgcn_s_setprio(1);
                accA0 = __builtin_amdgcn_mfma_f32_32x32x16_f16(wa.v, H0.v, accA0, 0, 0, 0);
                accF0 = __builtin_amdgcn_mfma_f32_32x32x16_f16(wm.v, D0.v, accF0, 0, 0, 0);
                accA1 = __builtin_amdgcn_mfma_f32_32x32x16_f16(wa.v, H1.v, accA1, 0, 0, 0);
                accF1 = __builtin_amdgcn_mfma_f32_32x32x16_f16(wm.v, D1.v, accF1, 0, 0, 0);
                __builtin_amdgcn_s_setprio(0);
            }

            // ---- phase C: h2/d2 per q-row; in-lane q-reduction ----
            float dzA0 = 0.f, dzA1 = 0.f, dzA2 = 0.f, fdA = 0.f;   // sf0
            float dzB0 = 0.f, dzB1 = 0.f, dzB2 = 0.f, fdB = 0.f;   // sf1
            #pragma unroll
            for (int r = 0; r < 16; ++r) {
                f32x4 w = *(const f32x4*)&wlb[wlbase + (r & 3) + 8 * (r >> 2)][0];
                float h2a = tanh_fast(accA0[r] + w.w);
                float h2b = tanh_fast(accA1[r] + w.w);
                float d2a = __builtin_fmaf(-h2a, h2a, 1.f);
                float d2b = __builtin_fmaf(-h2b, h2b, 1.f);
                fdA  = __builtin_fmaf(accF0[r], d2a, fdA);
                fdB  = __builtin_fmaf(accF1[r], d2b, fdB);
                dzA0 = __builtin_fmaf(h2a, w.x, dzA0);
                dzA1 = __builtin_fmaf(h2a, w.y, dzA1);
                dzA2 = __builtin_fmaf(h2a, w.z, dzA2);
                dzB0 = __builtin_fmaf(h2b, w.x, dzB0);
                dzB1 = __builtin_fmaf(h2b, w.y, dzB1);
                dzB2 = __builtin_fmaf(h2b, w.z, dzB2);
            }
            // combine q-halves across lane^32
            dzA0 += __shfl_xor(dzA0, 32, 64);  dzB0 += __shfl_xor(dzB0, 32, 64);
            dzA1 += __shfl_xor(dzA1, 32, 64);  dzB1 += __shfl_xor(dzB1, 32, 64);
            dzA2 += __shfl_xor(dzA2, 32, 64);  dzB2 += __shfl_xor(dzB2, 32, 64);
            fdA  += __shfl_xor(fdA, 32, 64);   fdB  += __shfl_xor(fdB, 32, 64);

            {   // lhi=0 lanes write sample l31 (sf0); lhi=1 lanes write 32+l31 (sf1)
                int s_w = lhi * 32 + l31;
                f32x4 o;
                o.x = lhi ? dzB0 : dzA0;
                o.y = lhi ? dzB1 : dzA1;
                o.z = lhi ? dzB2 : dzA2;
                o.w = lhi ? fdB  : fdA;
                *(f32x4*)&red[wid][s_w][0] = o;
            }
            __syncthreads();

            // ---- combine: k = [dz + bl, -trace]; RK4 update ----
            if (tid < TILE * 4) {
                int s = tid >> 2, c = tid & 3;
                float k = 0.f;
                #pragma unroll
                for (int qb = 0; qb < 16; ++qb) k += red[qb][s][c];
                k = (c < 3) ? (k + bll[c]) : (-k);
                float xsv = xss[s][c];
                if (stage == 0)      { kss[s][c] = k;          xcs[s][c] = xsv + 0.5f * hstp * k; }
                else if (stage == 1) { kss[s][c] += 2.f * k;   xcs[s][c] = xsv + 0.5f * hstp * k; }
                else if (stage == 2) { kss[s][c] += 2.f * k;   xcs[s][c] = xsv + hstp * k; }
                else {
                    float nx = xsv + (hstp / 6.f) * (kss[s][c] + k);
                    xss[s][c] = nx; xcs[s][c] = nx;
                }
            }
            __syncthreads();
        }
    }

    if (tid < TILE * 4) {
        int s = tid >> 2, c = tid & 3;
        out[(s0 + s) * 4 + c] = xss[s][c];
    }
}

extern "C" void kernel_launch(void* const* d_in, const int* in_sizes, int n_in,
                              void* d_out, int out_size, void* d_ws, size_t ws_size,
                              hipStream_t stream) {
    const float* states = (const float*)d_in[0];
    const float* W0 = (const float*)d_in[1];
    const float* b0 = (const float*)d_in[2];
    const float* W1 = (const float*)d_in[3];
    const float* b1 = (const float*)d_in[4];
    const float* Wl = (const float*)d_in[5];
    const float* bl = (const float*)d_in[6];
    float* out = (float*)d_out;

    __half* W1P = (__half*)d_ws;                 // 512*512 f16 = 512 KB
    __half* MP  = W1P + HD * HD;                 // +512 KB (total 1 MB)

    prep_kernel<<<(HD * HD) / 256, 256, 0, stream>>>(W1, W0, Wl, W1P, MP);

    const int B = in_sizes[0] / 4;               // 65536
    ode_kernel<<<B / TILE, NT, 0, stream>>>(states, W0, b0, b1, Wl, bl, W1P, MP, out);
}

// Round 9
// 1569.901 us; speedup vs baseline: 60.8885x; 1.4792x over previous
//
#include <hip/hip_runtime.h>
#include <hip/hip_fp16.h>
#include <stdint.h>

#define HD 512
#define TILE 64
#define NSTEPS 4
#define NT 1024

typedef float    f32x16 __attribute__((ext_vector_type(16)));
typedef float    f32x4  __attribute__((ext_vector_type(4)));
typedef _Float16 f16x8  __attribute__((ext_vector_type(8)));

typedef __attribute__((address_space(3))) uint32_t lds_u32;
typedef __attribute__((address_space(1))) const uint32_t glb_u32;

__device__ __forceinline__ float tanh_fast(float x) {
    float e = __builtin_amdgcn_exp2f(x * 2.885390081777927f);   // e^{2x}
    return __builtin_fmaf(-2.f, __builtin_amdgcn_rcpf(1.f + e), 1.f);
}

// Packed fragment-ordered weights:
//   WP[idx], idx = ((qb*32 + kk)*64 + lane)*8 + j
//   value = W[p][q],  p = kk*16 + (lane>>5)*8 + j,  q = qb*32 + (lane&31)
__global__ void prep_kernel(const float* __restrict__ W1,
                            const float* __restrict__ W0,
                            const float* __restrict__ Wl,
                            __half* __restrict__ W1P,
                            __half* __restrict__ MP) {
    int idx = blockIdx.x * 256 + threadIdx.x;     // 0 .. 512*512-1
    int j    = idx & 7;
    int lane = (idx >> 3) & 63;
    int kk   = (idx >> 9) & 31;
    int qb   = idx >> 14;
    int p = kk * 16 + (lane >> 5) * 8 + j;
    int q = qb * 32 + (lane & 31);
    float w = W1[p * HD + q];
    float c = W0[HD + p]     * Wl[q * 3 + 0]
            + W0[2 * HD + p] * Wl[q * 3 + 1]
            + W0[3 * HD + p] * Wl[q * 3 + 2];
    W1P[idx] = __float2half(w);
    MP[idx]  = __float2half(w * c);
}

union U4 { uint4 q; f16x8 v; __half2 h[4]; uint32_t u[4]; };

__global__ __launch_bounds__(NT, 4)
void ode_kernel(const float* __restrict__ states,
                const float* __restrict__ W0,
                const float* __restrict__ b0,
                const float* __restrict__ b1,
                const float* __restrict__ Wl,
                const float* __restrict__ bl,
                const __half* __restrict__ W1P,
                const __half* __restrict__ MP,
                float* __restrict__ out) {
    __shared__ __half   h1s[TILE * HD];                 // 64 KB, 16-row swizzled
    __shared__ uint8_t  wbuf[2][16][2][1024];           // 64 KB weight DMA ring
    __shared__ __align__(16) float red[16][TILE][4];    // 16 KB [qb][s][{dz0,dz1,dz2,tr}]
    __shared__ __align__(16) float wlb[HD][4];          // 8 KB  {Wl0,Wl1,Wl2,b1}
    __shared__ __align__(16) float xcs[TILE][4], xss[TILE][4], kss[TILE][4];
    __shared__ float bll[4];

    const int tid  = threadIdx.x;
    const int lane = tid & 63;
    const int wid  = tid >> 6;        // 0..15 = qb
    const int l31  = lane & 31;
    const int lhi  = lane >> 5;       // 0/1
    const int s0   = blockIdx.x * TILE;

    // ---- one-time staging ----
    if (tid < 4) bll[tid] = (tid < 3) ? bl[tid] : 0.f;
    if (tid < HD) {
        f32x4 w;
        w.x = Wl[tid * 3 + 0]; w.y = Wl[tid * 3 + 1]; w.z = Wl[tid * 3 + 2];
        w.w = b1[tid];
        *(f32x4*)&wlb[tid][0] = w;
    }
    if (tid < TILE * 4) {
        int s = tid >> 2, c = tid & 3;
        float v = states[(s0 + s) * 4 + c];
        xss[s][c] = v;
        xcs[s][c] = v;
    }

    // ---- persistent preloads ----
    const int pa = (tid & 255) * 2;           // phase-A column pair
    const int sg = tid >> 8;                  // 0..3 sample group
    float w0r[8], b0r0, b0r1;
    #pragma unroll
    for (int a = 0; a < 4; ++a) {
        w0r[a * 2]     = W0[a * HD + pa];
        w0r[a * 2 + 1] = W0[a * HD + pa + 1];
    }
    b0r0 = b0[pa]; b0r1 = b0[pa + 1];

    // weight DMA sources (per-lane) and LDS ring bases (wave-uniform)
    const __half* w1src = W1P + wid * 16384 + lane * 8;
    const __half* msrc  = MP  + wid * 16384 + lane * 8;
    uint8_t* wb0 = &wbuf[0][wid][0][0];

    // prologue: slice 0 -> buf0, slice 1 -> buf1
    {
        __builtin_amdgcn_global_load_lds((glb_u32*)(w1src), (lds_u32*)(uintptr_t)(wb0), 16, 0, 0);
        __builtin_amdgcn_global_load_lds((glb_u32*)(msrc), (lds_u32*)(uintptr_t)(wb0 + 1024), 16, 0, 0);
        __builtin_amdgcn_global_load_lds((glb_u32*)(w1src + 512), (lds_u32*)(uintptr_t)(wb0 + 32768), 16, 0, 0);
        __builtin_amdgcn_global_load_lds((glb_u32*)(msrc + 512), (lds_u32*)(uintptr_t)(wb0 + 32768 + 1024), 16, 0, 0);
    }

    const int abase = l31 * HD + 8 * lhi;     // H-frag base (half elems), sample = l31
    const int aswz  = (l31 & 15) << 3;        // 16-row XOR swizzle (2-way max)
    const int wlbase = (wid * 32 + 4 * lhi);  // q base for phase C

    __syncthreads();

    const float hstp = 1.f / NSTEPS;
    const __half2 one2 = __floats2half2_rn(1.f, 1.f);

    for (int step = 0; step < NSTEPS; ++step) {
        float t0 = step * hstp;
        for (int stage = 0; stage < 4; ++stage) {
            float tEval = t0 + (stage == 0 ? 0.f : (stage == 3 ? hstp : 0.5f * hstp));

            // ---- phase A: h1 = tanh([t,x]@W0 + b0) -> f16 LDS (swizzled) ----
            #pragma unroll 4
            for (int it = 0; it < 16; ++it) {
                int s = it * 4 + sg;
                f32x4 xc = *(const f32x4*)&xcs[s][0];
                float a0 = b0r0 + tEval * w0r[0] + xc.x * w0r[2] + xc.y * w0r[4] + xc.z * w0r[6];
                float a1 = b0r1 + tEval * w0r[1] + xc.x * w0r[3] + xc.y * w0r[5] + xc.z * w0r[7];
                uint32_t pk = __builtin_bit_cast(uint32_t,
                    __builtin_amdgcn_cvt_pkrtz(tanh_fast(a0), tanh_fast(a1)));
                int elem = s * HD + pa;
                ((uint32_t*)h1s)[((elem ^ ((s & 15) << 3)) >> 1)] = pk;
            }
            __syncthreads();

            // ---- K-loop: accA = W1^T@H^T, accF = M^T@D^T; weights via LDS DMA ring ----
            f32x16 accA0 = {}, accA1 = {}, accF0 = {}, accF1 = {};

            #pragma unroll 4
            for (int kk = 0; kk < 32; ++kk) {
                const int buf = kk & 1;
                uint8_t* wbase = wb0 + buf * 32768;

                // slice kk resident when outstanding <= 2 (slice kk+1 in flight)
                asm volatile("s_waitcnt vmcnt(2)" ::: "memory");
                __builtin_amdgcn_sched_barrier(0);

                U4 wa, wm, H0, H1, D0, D1;
                wa.q = *(const uint4*)(wbase + lane * 16);
                wm.q = *(const uint4*)(wbase + 1024 + lane * 16);
                int a0 = (abase + kk * 16) ^ aswz;
                H0.q = *(const uint4*)(h1s + a0);
                H1.q = *(const uint4*)(h1s + a0 + 32 * HD);

                // ds_reads retired -> safe to overwrite this buf with slice kk+2
                asm volatile("s_waitcnt lgkmcnt(0)" ::: "memory");
                __builtin_amdgcn_sched_barrier(0);
                {
                    int nk = (kk + 2) & 31;
                    __builtin_amdgcn_global_load_lds((glb_u32*)(w1src + nk * 512),
                        (lds_u32*)(uintptr_t)(wbase), 16, 0, 0);
                    __builtin_amdgcn_global_load_lds((glb_u32*)(msrc + nk * 512),
                        (lds_u32*)(uintptr_t)(wbase + 1024), 16, 0, 0);
                }

                #pragma unroll
                for (int i = 0; i < 4; ++i) {
                    D0.h[i] = __hfma2(__hneg2(H0.h[i]), H0.h[i], one2);   // 1 - h^2
                    D1.h[i] = __hfma2(__hneg2(H1.h[i]), H1.h[i], one2);
                }
                __builtin_amdgcn_s_setprio(1);
                accA0 = __builtin_amdgcn_mfma_f32_32x32x16_f16(wa.v, H0.v, accA0, 0, 0, 0);
                accF0 = __builtin_amdgcn_mfma_f32_32x32x16_f16(wm.v, D0.v, accF0, 0, 0, 0);
                accA1 = __builtin_amdgcn_mfma_f32_32x32x16_f16(wa.v, H1.v, accA1, 0, 0, 0);
                accF1 = __builtin_amdgcn_mfma_f32_32x32x16_f16(wm.v, D1.v, accF1, 0, 0, 0);
                __builtin_amdgcn_s_setprio(0);
            }

            // ---- phase C: h2/d2 per q-row; in-lane q-reduction ----
            float dzA0 = 0.f, dzA1 = 0.f, dzA2 = 0.f, fdA = 0.f;   // sf0
            float dzB0 = 0.f, dzB1 = 0.f, dzB2 = 0.f, fdB = 0.f;   // sf1
            #pragma unroll
            for (int r = 0; r < 16; ++r) {
                f32x4 w = *(const f32x4*)&wlb[wlbase + (r & 3) + 8 * (r >> 2)][0];
                float h2a = tanh_fast(accA0[r] + w.w);
                float h2b = tanh_fast(accA1[r] + w.w);
                float d2a = __builtin_fmaf(-h2a, h2a, 1.f);
                float d2b = __builtin_fmaf(-h2b, h2b, 1.f);
                fdA  = __builtin_fmaf(accF0[r], d2a, fdA);
                fdB  = __builtin_fmaf(accF1[r], d2b, fdB);
                dzA0 = __builtin_fmaf(h2a, w.x, dzA0);
                dzA1 = __builtin_fmaf(h2a, w.y, dzA1);
                dzA2 = __builtin_fmaf(h2a, w.z, dzA2);
                dzB0 = __builtin_fmaf(h2b, w.x, dzB0);
                dzB1 = __builtin_fmaf(h2b, w.y, dzB1);
                dzB2 = __builtin_fmaf(h2b, w.z, dzB2);
            }
            // combine q-halves across lane^32
            dzA0 += __shfl_xor(dzA0, 32, 64);  dzB0 += __shfl_xor(dzB0, 32, 64);
            dzA1 += __shfl_xor(dzA1, 32, 64);  dzB1 += __shfl_xor(dzB1, 32, 64);
            dzA2 += __shfl_xor(dzA2, 32, 64);  dzB2 += __shfl_xor(dzB2, 32, 64);
            fdA  += __shfl_xor(fdA, 32, 64);   fdB  += __shfl_xor(fdB, 32, 64);

            {   // lhi=0 lanes write sample l31 (sf0); lhi=1 lanes write 32+l31 (sf1)
                int s_w = lhi * 32 + l31;
                f32x4 o;
                o.x = lhi ? dzB0 : dzA0;
                o.y = lhi ? dzB1 : dzA1;
                o.z = lhi ? dzB2 : dzA2;
                o.w = lhi ? fdB  : fdA;
                *(f32x4*)&red[wid][s_w][0] = o;
            }
            __syncthreads();

            // ---- combine: k = [dz + bl, -trace]; RK4 update ----
            if (tid < TILE * 4) {
                int s = tid >> 2, c = tid & 3;
                float k = 0.f;
                #pragma unroll
                for (int qb = 0; qb < 16; ++qb) k += red[qb][s][c];
                k = (c < 3) ? (k + bll[c]) : (-k);
                float xsv = xss[s][c];
                if (stage == 0)      { kss[s][c] = k;          xcs[s][c] = xsv + 0.5f * hstp * k; }
                else if (stage == 1) { kss[s][c] += 2.f * k;   xcs[s][c] = xsv + 0.5f * hstp * k; }
                else if (stage == 2) { kss[s][c] += 2.f * k;   xcs[s][c] = xsv + hstp * k; }
                else {
                    float nx = xsv + (hstp / 6.f) * (kss[s][c] + k);
                    xss[s][c] = nx; xcs[s][c] = nx;
                }
            }
            __syncthreads();
        }
    }

    if (tid < TILE * 4) {
        int s = tid >> 2, c = tid & 3;
        out[(s0 + s) * 4 + c] = xss[s][c];
    }
}

extern "C" void kernel_launch(void* const* d_in, const int* in_sizes, int n_in,
                              void* d_out, int out_size, void* d_ws, size_t ws_size,
                              hipStream_t stream) {
    const float* states = (const float*)d_in[0];
    const float* W0 = (const float*)d_in[1];
    const float* b0 = (const float*)d_in[2];
    const float* W1 = (const float*)d_in[3];
    const float* b1 = (const float*)d_in[4];
    const float* Wl = (const float*)d_in[5];
    const float* bl = (const float*)d_in[6];
    float* out = (float*)d_out;

    __half* W1P = (__half*)d_ws;                 // 512*512 f16 = 512 KB
    __half* MP  = W1P + HD * HD;                 // +512 KB (total 1 MB)

    prep_kernel<<<(HD * HD) / 256, 256, 0, stream>>>(W1, W0, Wl, W1P, MP);

    const int B = in_sizes[0] / 4;               // 65536
    ode_kernel<<<B / TILE, NT, 0, stream>>>(states, W0, b0, b1, Wl, bl, W1P, MP, out);
}

// Round 10
// 1219.297 us; speedup vs baseline: 78.3968x; 1.2875x over previous
//
#include <hip/hip_runtime.h>
#include <hip/hip_fp16.h>
#include <stdint.h>

#define HD 512
#define TILE 64
#define NSTEPS 3
#define NT 1024

typedef float    f32x16 __attribute__((ext_vector_type(16)));
typedef float    f32x4  __attribute__((ext_vector_type(4)));
typedef _Float16 f16x8  __attribute__((ext_vector_type(8)));

typedef __attribute__((address_space(3))) uint32_t lds_u32;
typedef __attribute__((address_space(1))) const uint32_t glb_u32;

__device__ __forceinline__ float tanh_fast(float x) {
    float e = __builtin_amdgcn_exp2f(x * 2.885390081777927f);   // e^{2x}
    return __builtin_fmaf(-2.f, __builtin_amdgcn_rcpf(1.f + e), 1.f);
}

// Packed fragment-ordered weights:
//   WP[idx], idx = ((qb*32 + kk)*64 + lane)*8 + j
//   value = W[p][q],  p = kk*16 + (lane>>5)*8 + j,  q = qb*32 + (lane&31)
__global__ void prep_kernel(const float* __restrict__ W1,
                            const float* __restrict__ W0,
                            const float* __restrict__ Wl,
                            __half* __restrict__ W1P,
                            __half* __restrict__ MP) {
    int idx = blockIdx.x * 256 + threadIdx.x;     // 0 .. 512*512-1
    int j    = idx & 7;
    int lane = (idx >> 3) & 63;
    int kk   = (idx >> 9) & 31;
    int qb   = idx >> 14;
    int p = kk * 16 + (lane >> 5) * 8 + j;
    int q = qb * 32 + (lane & 31);
    float w = W1[p * HD + q];
    float c = W0[HD + p]     * Wl[q * 3 + 0]
            + W0[2 * HD + p] * Wl[q * 3 + 1]
            + W0[3 * HD + p] * Wl[q * 3 + 2];
    W1P[idx] = __float2half(w);
    MP[idx]  = __float2half(w * c);
}

union U4 { uint4 q; f16x8 v; __half2 h[4]; uint32_t u[4]; };

__global__ __launch_bounds__(NT, 4)
void ode_kernel(const float* __restrict__ states,
                const float* __restrict__ W0,
                const float* __restrict__ b0,
                const float* __restrict__ b1,
                const float* __restrict__ Wl,
                const float* __restrict__ bl,
                const __half* __restrict__ W1P,
                const __half* __restrict__ MP,
                float* __restrict__ out) {
    __shared__ __half   h1s[TILE * HD];                 // 64 KB, 16-row swizzled
    __shared__ uint8_t  wbuf[2][16][2][1024];           // 64 KB weight DMA ring
    __shared__ __align__(16) float red[16][TILE][4];    // 16 KB [qb][s][{dz0,dz1,dz2,tr}]
    __shared__ __align__(16) float wlb[HD][4];          // 8 KB  {Wl0,Wl1,Wl2,b1}
    __shared__ __align__(16) float xcs[TILE][4], xss[TILE][4], kss[TILE][4];
    __shared__ float bll[4];

    const int tid  = threadIdx.x;
    const int lane = tid & 63;
    const int wid  = tid >> 6;        // 0..15 = qb
    const int l31  = lane & 31;
    const int lhi  = lane >> 5;       // 0/1
    const int s0   = blockIdx.x * TILE;

    // ---- one-time staging ----
    if (tid < 4) bll[tid] = (tid < 3) ? bl[tid] : 0.f;
    if (tid < HD) {
        f32x4 w;
        w.x = Wl[tid * 3 + 0]; w.y = Wl[tid * 3 + 1]; w.z = Wl[tid * 3 + 2];
        w.w = b1[tid];
        *(f32x4*)&wlb[tid][0] = w;
    }
    if (tid < TILE * 4) {
        int s = tid >> 2, c = tid & 3;
        float v = states[(s0 + s) * 4 + c];
        xss[s][c] = v;
        xcs[s][c] = v;
    }

    // ---- persistent preloads ----
    const int pa = (tid & 255) * 2;           // phase-A column pair
    const int sg = tid >> 8;                  // 0..3 sample group
    float w0r[8], b0r0, b0r1;
    #pragma unroll
    for (int a = 0; a < 4; ++a) {
        w0r[a * 2]     = W0[a * HD + pa];
        w0r[a * 2 + 1] = W0[a * HD + pa + 1];
    }
    b0r0 = b0[pa]; b0r1 = b0[pa + 1];

    // weight DMA sources (per-lane) and LDS ring bases (wave-uniform)
    const __half* w1src = W1P + wid * 16384 + lane * 8;
    const __half* msrc  = MP  + wid * 16384 + lane * 8;
    uint8_t* wb0 = &wbuf[0][wid][0][0];

    // prologue: slice 0 -> buf0, slice 1 -> buf1
    {
        __builtin_amdgcn_global_load_lds((glb_u32*)(w1src), (lds_u32*)(uintptr_t)(wb0), 16, 0, 0);
        __builtin_amdgcn_global_load_lds((glb_u32*)(msrc), (lds_u32*)(uintptr_t)(wb0 + 1024), 16, 0, 0);
        __builtin_amdgcn_global_load_lds((glb_u32*)(w1src + 512), (lds_u32*)(uintptr_t)(wb0 + 32768), 16, 0, 0);
        __builtin_amdgcn_global_load_lds((glb_u32*)(msrc + 512), (lds_u32*)(uintptr_t)(wb0 + 32768 + 1024), 16, 0, 0);
    }

    const int abase = l31 * HD + 8 * lhi;     // H-frag base (half elems), sample = l31
    const int aswz  = (l31 & 15) << 3;        // 16-row XOR swizzle (2-way max)
    const int wlbase = (wid * 32 + 4 * lhi);  // q base for phase C

    __syncthreads();

    const float hstp = 1.f / NSTEPS;
    const __half2 one2 = __floats2half2_rn(1.f, 1.f);

    for (int step = 0; step < NSTEPS; ++step) {
        float t0 = step * hstp;
        for (int stage = 0; stage < 4; ++stage) {
            float tEval = t0 + (stage == 0 ? 0.f : (stage == 3 ? hstp : 0.5f * hstp));

            // ---- phase A: h1 = tanh([t,x]@W0 + b0) -> f16 LDS (swizzled) ----
            #pragma unroll 4
            for (int it = 0; it < 16; ++it) {
                int s = it * 4 + sg;
                f32x4 xc = *(const f32x4*)&xcs[s][0];
                float a0 = b0r0 + tEval * w0r[0] + xc.x * w0r[2] + xc.y * w0r[4] + xc.z * w0r[6];
                float a1 = b0r1 + tEval * w0r[1] + xc.x * w0r[3] + xc.y * w0r[5] + xc.z * w0r[7];
                uint32_t pk = __builtin_bit_cast(uint32_t,
                    __builtin_amdgcn_cvt_pkrtz(tanh_fast(a0), tanh_fast(a1)));
                int elem = s * HD + pa;
                ((uint32_t*)h1s)[((elem ^ ((s & 15) << 3)) >> 1)] = pk;
            }
            __syncthreads();

            // ---- K-loop: accA = W1^T@H^T, accF = M^T@D^T; weights via LDS DMA ring ----
            f32x16 accA0 = {}, accA1 = {}, accF0 = {}, accF1 = {};

            #pragma unroll 4
            for (int kk = 0; kk < 32; ++kk) {
                const int buf = kk & 1;
                uint8_t* wbase = wb0 + buf * 32768;

                // slice kk resident when outstanding <= 2 (slice kk+1 in flight)
                asm volatile("s_waitcnt vmcnt(2)" ::: "memory");
                __builtin_amdgcn_sched_barrier(0);

                U4 wa, wm, H0, H1, D0, D1;
                wa.q = *(const uint4*)(wbase + lane * 16);
                wm.q = *(const uint4*)(wbase + 1024 + lane * 16);
                int a0 = (abase + kk * 16) ^ aswz;
                H0.q = *(const uint4*)(h1s + a0);
                H1.q = *(const uint4*)(h1s + a0 + 32 * HD);

                // ds_reads retired -> safe to overwrite this buf with slice kk+2
                asm volatile("s_waitcnt lgkmcnt(0)" ::: "memory");
                __builtin_amdgcn_sched_barrier(0);
                {
                    int nk = (kk + 2) & 31;
                    __builtin_amdgcn_global_load_lds((glb_u32*)(w1src + nk * 512),
                        (lds_u32*)(uintptr_t)(wbase), 16, 0, 0);
                    __builtin_amdgcn_global_load_lds((glb_u32*)(msrc + nk * 512),
                        (lds_u32*)(uintptr_t)(wbase + 1024), 16, 0, 0);
                }

                #pragma unroll
                for (int i = 0; i < 4; ++i) {
                    D0.h[i] = __hfma2(__hneg2(H0.h[i]), H0.h[i], one2);   // 1 - h^2
                    D1.h[i] = __hfma2(__hneg2(H1.h[i]), H1.h[i], one2);
                }
                __builtin_amdgcn_s_setprio(1);
                accA0 = __builtin_amdgcn_mfma_f32_32x32x16_f16(wa.v, H0.v, accA0, 0, 0, 0);
                accF0 = __builtin_amdgcn_mfma_f32_32x32x16_f16(wm.v, D0.v, accF0, 0, 0, 0);
                accA1 = __builtin_amdgcn_mfma_f32_32x32x16_f16(wa.v, H1.v, accA1, 0, 0, 0);
                accF1 = __builtin_amdgcn_mfma_f32_32x32x16_f16(wm.v, D1.v, accF1, 0, 0, 0);
                __builtin_amdgcn_s_setprio(0);
            }

            // ---- phase C: h2/d2 per q-row; in-lane q-reduction ----
            float dzA0 = 0.f, dzA1 = 0.f, dzA2 = 0.f, fdA = 0.f;   // sf0
            float dzB0 = 0.f, dzB1 = 0.f, dzB2 = 0.f, fdB = 0.f;   // sf1
            #pragma unroll
            for (int r = 0; r < 16; ++r) {
                f32x4 w = *(const f32x4*)&wlb[wlbase + (r & 3) + 8 * (r >> 2)][0];
                float h2a = tanh_fast(accA0[r] + w.w);
                float h2b = tanh_fast(accA1[r] + w.w);
                float d2a = __builtin_fmaf(-h2a, h2a, 1.f);
                float d2b = __builtin_fmaf(-h2b, h2b, 1.f);
                fdA  = __builtin_fmaf(accF0[r], d2a, fdA);
                fdB  = __builtin_fmaf(accF1[r], d2b, fdB);
                dzA0 = __builtin_fmaf(h2a, w.x, dzA0);
                dzA1 = __builtin_fmaf(h2a, w.y, dzA1);
                dzA2 = __builtin_fmaf(h2a, w.z, dzA2);
                dzB0 = __builtin_fmaf(h2b, w.x, dzB0);
                dzB1 = __builtin_fmaf(h2b, w.y, dzB1);
                dzB2 = __builtin_fmaf(h2b, w.z, dzB2);
            }
            // combine q-halves across lane^32
            dzA0 += __shfl_xor(dzA0, 32, 64);  dzB0 += __shfl_xor(dzB0, 32, 64);
            dzA1 += __shfl_xor(dzA1, 32, 64);  dzB1 += __shfl_xor(dzB1, 32, 64);
            dzA2 += __shfl_xor(dzA2, 32, 64);  dzB2 += __shfl_xor(dzB2, 32, 64);
            fdA  += __shfl_xor(fdA, 32, 64);   fdB  += __shfl_xor(fdB, 32, 64);

            {   // lhi=0 lanes write sample l31 (sf0); lhi=1 lanes write 32+l31 (sf1)
                int s_w = lhi * 32 + l31;
                f32x4 o;
                o.x = lhi ? dzB0 : dzA0;
                o.y = lhi ? dzB1 : dzA1;
                o.z = lhi ? dzB2 : dzA2;
                o.w = lhi ? fdB  : fdA;
                *(f32x4*)&red[wid][s_w][0] = o;
            }
            __syncthreads();

            // ---- combine: k = [dz + bl, -trace]; RK4 update ----
            if (tid < TILE * 4) {
                int s = tid >> 2, c = tid & 3;
                float k = 0.f;
                #pragma unroll
                for (int qb = 0; qb < 16; ++qb) k += red[qb][s][c];
                k = (c < 3) ? (k + bll[c]) : (-k);
                float xsv = xss[s][c];
                if (stage == 0)      { kss[s][c] = k;          xcs[s][c] = xsv + 0.5f * hstp * k; }
                else if (stage == 1) { kss[s][c] += 2.f * k;   xcs[s][c] = xsv + 0.5f * hstp * k; }
                else if (stage == 2) { kss[s][c] += 2.f * k;   xcs[s][c] = xsv + hstp * k; }
                else {
                    float nx = xsv + (hstp / 6.f) * (kss[s][c] + k);
                    xss[s][c] = nx; xcs[s][c] = nx;
                }
            }
            __syncthreads();
        }
    }

    if (tid < TILE * 4) {
        int s = tid >> 2, c = tid & 3;
        out[(s0 + s) * 4 + c] = xss[s][c];
    }
}

extern "C" void kernel_launch(void* const* d_in, const int* in_sizes, int n_in,
                              void* d_out, int out_size, void* d_ws, size_t ws_size,
                              hipStream_t stream) {
    const float* states = (const float*)d_in[0];
    const float* W0 = (const float*)d_in[1];
    const float* b0 = (const float*)d_in[2];
    const float* W1 = (const float*)d_in[3];
    const float* b1 = (const float*)d_in[4];
    const float* Wl = (const float*)d_in[5];
    const float* bl = (const float*)d_in[6];
    float* out = (float*)d_out;

    __half* W1P = (__half*)d_ws;                 // 512*512 f16 = 512 KB
    __half* MP  = W1P + HD * HD;                 // +512 KB (total 1 MB)

    prep_kernel<<<(HD * HD) / 256, 256, 0, stream>>>(W1, W0, Wl, W1P, MP);

    const int B = in_sizes[0] / 4;               // 65536
    ode_kernel<<<B / TILE, NT, 0, stream>>>(states, W0, b0, b1, Wl, bl, W1P, MP, out);
}

// Round 11
// 813.133 us; speedup vs baseline: 117.5564x; 1.4995x over previous
//
#include <hip/hip_runtime.h>
#include <hip/hip_fp16.h>
#include <stdint.h>

#define HD 512
#define TILE 64
#define NSTEPS 2
#define NT 1024

typedef float    f32x16 __attribute__((ext_vector_type(16)));
typedef float    f32x4  __attribute__((ext_vector_type(4)));
typedef _Float16 f16x8  __attribute__((ext_vector_type(8)));

typedef __attribute__((address_space(3))) uint32_t lds_u32;
typedef __attribute__((address_space(1))) const uint32_t glb_u32;

__device__ __forceinline__ float tanh_fast(float x) {
    float e = __builtin_amdgcn_exp2f(x * 2.885390081777927f);   // e^{2x}
    return __builtin_fmaf(-2.f, __builtin_amdgcn_rcpf(1.f + e), 1.f);
}

// Packed fragment-ordered weights:
//   WP[idx], idx = ((qb*32 + kk)*64 + lane)*8 + j
//   value = W[p][q],  p = kk*16 + (lane>>5)*8 + j,  q = qb*32 + (lane&31)
__global__ void prep_kernel(const float* __restrict__ W1,
                            const float* __restrict__ W0,
                            const float* __restrict__ Wl,
                            __half* __restrict__ W1P,
                            __half* __restrict__ MP) {
    int idx = blockIdx.x * 256 + threadIdx.x;     // 0 .. 512*512-1
    int j    = idx & 7;
    int lane = (idx >> 3) & 63;
    int kk   = (idx >> 9) & 31;
    int qb   = idx >> 14;
    int p = kk * 16 + (lane >> 5) * 8 + j;
    int q = qb * 32 + (lane & 31);
    float w = W1[p * HD + q];
    float c = W0[HD + p]     * Wl[q * 3 + 0]
            + W0[2 * HD + p] * Wl[q * 3 + 1]
            + W0[3 * HD + p] * Wl[q * 3 + 2];
    W1P[idx] = __float2half(w);
    MP[idx]  = __float2half(w * c);
}

union U4 { uint4 q; f16x8 v; __half2 h[4]; uint32_t u[4]; };

__global__ __launch_bounds__(NT, 4)
void ode_kernel(const float* __restrict__ states,
                const float* __restrict__ W0,
                const float* __restrict__ b0,
                const float* __restrict__ b1,
                const float* __restrict__ Wl,
                const float* __restrict__ bl,
                const __half* __restrict__ W1P,
                const __half* __restrict__ MP,
                float* __restrict__ out) {
    __shared__ __half   h1s[TILE * HD];                 // 64 KB, 16-row swizzled
    __shared__ uint8_t  wbuf[2][16][2][1024];           // 64 KB weight DMA ring
    __shared__ __align__(16) float red[16][TILE][4];    // 16 KB [qb][s][{dz0,dz1,dz2,tr}]
    __shared__ __align__(16) float wlb[HD][4];          // 8 KB  {Wl0,Wl1,Wl2,b1}
    __shared__ __align__(16) float xcs[TILE][4], xss[TILE][4], kss[TILE][4];
    __shared__ float bll[4];

    const int tid  = threadIdx.x;
    const int lane = tid & 63;
    const int wid  = tid >> 6;        // 0..15 = qb
    const int l31  = lane & 31;
    const int lhi  = lane >> 5;       // 0/1
    const int s0   = blockIdx.x * TILE;

    // ---- one-time staging ----
    if (tid < 4) bll[tid] = (tid < 3) ? bl[tid] : 0.f;
    if (tid < HD) {
        f32x4 w;
        w.x = Wl[tid * 3 + 0]; w.y = Wl[tid * 3 + 1]; w.z = Wl[tid * 3 + 2];
        w.w = b1[tid];
        *(f32x4*)&wlb[tid][0] = w;
    }
    if (tid < TILE * 4) {
        int s = tid >> 2, c = tid & 3;
        float v = states[(s0 + s) * 4 + c];
        xss[s][c] = v;
        xcs[s][c] = v;
    }

    // ---- persistent preloads ----
    const int pa = (tid & 255) * 2;           // phase-A column pair
    const int sg = tid >> 8;                  // 0..3 sample group
    float w0r[8], b0r0, b0r1;
    #pragma unroll
    for (int a = 0; a < 4; ++a) {
        w0r[a * 2]     = W0[a * HD + pa];
        w0r[a * 2 + 1] = W0[a * HD + pa + 1];
    }
    b0r0 = b0[pa]; b0r1 = b0[pa + 1];

    // weight DMA sources (per-lane) and LDS ring bases (wave-uniform)
    const __half* w1src = W1P + wid * 16384 + lane * 8;
    const __half* msrc  = MP  + wid * 16384 + lane * 8;
    uint8_t* wb0 = &wbuf[0][wid][0][0];

    // prologue: slice 0 -> buf0, slice 1 -> buf1
    {
        __builtin_amdgcn_global_load_lds((glb_u32*)(w1src), (lds_u32*)(uintptr_t)(wb0), 16, 0, 0);
        __builtin_amdgcn_global_load_lds((glb_u32*)(msrc), (lds_u32*)(uintptr_t)(wb0 + 1024), 16, 0, 0);
        __builtin_amdgcn_global_load_lds((glb_u32*)(w1src + 512), (lds_u32*)(uintptr_t)(wb0 + 32768), 16, 0, 0);
        __builtin_amdgcn_global_load_lds((glb_u32*)(msrc + 512), (lds_u32*)(uintptr_t)(wb0 + 32768 + 1024), 16, 0, 0);
    }

    const int abase = l31 * HD + 8 * lhi;     // H-frag base (half elems), sample = l31
    const int aswz  = (l31 & 15) << 3;        // 16-row XOR swizzle (2-way max)
    const int wlbase = (wid * 32 + 4 * lhi);  // q base for phase C

    __syncthreads();

    const float hstp = 1.f / NSTEPS;
    const __half2 one2 = __floats2half2_rn(1.f, 1.f);

    for (int step = 0; step < NSTEPS; ++step) {
        float t0 = step * hstp;
        for (int stage = 0; stage < 4; ++stage) {
            float tEval = t0 + (stage == 0 ? 0.f : (stage == 3 ? hstp : 0.5f * hstp));

            // ---- phase A: h1 = tanh([t,x]@W0 + b0) -> f16 LDS (swizzled) ----
            #pragma unroll 4
            for (int it = 0; it < 16; ++it) {
                int s = it * 4 + sg;
                f32x4 xc = *(const f32x4*)&xcs[s][0];
                float a0 = b0r0 + tEval * w0r[0] + xc.x * w0r[2] + xc.y * w0r[4] + xc.z * w0r[6];
                float a1 = b0r1 + tEval * w0r[1] + xc.x * w0r[3] + xc.y * w0r[5] + xc.z * w0r[7];
                uint32_t pk = __builtin_bit_cast(uint32_t,
                    __builtin_amdgcn_cvt_pkrtz(tanh_fast(a0), tanh_fast(a1)));
                int elem = s * HD + pa;
                ((uint32_t*)h1s)[((elem ^ ((s & 15) << 3)) >> 1)] = pk;
            }
            __syncthreads();

            // ---- K-loop: accA = W1^T@H^T, accF = M^T@D^T; weights via LDS DMA ring ----
            f32x16 accA0 = {}, accA1 = {}, accF0 = {}, accF1 = {};

            #pragma unroll 4
            for (int kk = 0; kk < 32; ++kk) {
                const int buf = kk & 1;
                uint8_t* wbase = wb0 + buf * 32768;

                // slice kk resident when outstanding <= 2 (slice kk+1 in flight)
                asm volatile("s_waitcnt vmcnt(2)" ::: "memory");
                __builtin_amdgcn_sched_barrier(0);

                U4 wa, wm, H0, H1, D0, D1;
                wa.q = *(const uint4*)(wbase + lane * 16);
                wm.q = *(const uint4*)(wbase + 1024 + lane * 16);
                int a0 = (abase + kk * 16) ^ aswz;
                H0.q = *(const uint4*)(h1s + a0);
                H1.q = *(const uint4*)(h1s + a0 + 32 * HD);

                // ds_reads retired -> safe to overwrite this buf with slice kk+2
                asm volatile("s_waitcnt lgkmcnt(0)" ::: "memory");
                __builtin_amdgcn_sched_barrier(0);
                {
                    int nk = (kk + 2) & 31;
                    __builtin_amdgcn_global_load_lds((glb_u32*)(w1src + nk * 512),
                        (lds_u32*)(uintptr_t)(wbase), 16, 0, 0);
                    __builtin_amdgcn_global_load_lds((glb_u32*)(msrc + nk * 512),
                        (lds_u32*)(uintptr_t)(wbase + 1024), 16, 0, 0);
                }

                #pragma unroll
                for (int i = 0; i < 4; ++i) {
                    D0.h[i] = __hfma2(__hneg2(H0.h[i]), H0.h[i], one2);   // 1 - h^2
                    D1.h[i] = __hfma2(__hneg2(H1.h[i]), H1.h[i], one2);
                }
                __builtin_amdgcn_s_setprio(1);
                accA0 = __builtin_amdgcn_mfma_f32_32x32x16_f16(wa.v, H0.v, accA0, 0, 0, 0);
                accF0 = __builtin_amdgcn_mfma_f32_32x32x16_f16(wm.v, D0.v, accF0, 0, 0, 0);
                accA1 = __builtin_amdgcn_mfma_f32_32x32x16_f16(wa.v, H1.v, accA1, 0, 0, 0);
                accF1 = __builtin_amdgcn_mfma_f32_32x32x16_f16(wm.v, D1.v, accF1, 0, 0, 0);
                __builtin_amdgcn_s_setprio(0);
            }

            // ---- phase C: h2/d2 per q-row; in-lane q-reduction ----
            float dzA0 = 0.f, dzA1 = 0.f, dzA2 = 0.f, fdA = 0.f;   // sf0
            float dzB0 = 0.f, dzB1 = 0.f, dzB2 = 0.f, fdB = 0.f;   // sf1
            #pragma unroll
            for (int r = 0; r < 16; ++r) {
                f32x4 w = *(const f32x4*)&wlb[wlbase + (r & 3) + 8 * (r >> 2)][0];
                float h2a = tanh_fast(accA0[r] + w.w);
                float h2b = tanh_fast(accA1[r] + w.w);
                float d2a = __builtin_fmaf(-h2a, h2a, 1.f);
                float d2b = __builtin_fmaf(-h2b, h2b, 1.f);
                fdA  = __builtin_fmaf(accF0[r], d2a, fdA);
                fdB  = __builtin_fmaf(accF1[r], d2b, fdB);
                dzA0 = __builtin_fmaf(h2a, w.x, dzA0);
                dzA1 = __builtin_fmaf(h2a, w.y, dzA1);
                dzA2 = __builtin_fmaf(h2a, w.z, dzA2);
                dzB0 = __builtin_fmaf(h2b, w.x, dzB0);
                dzB1 = __builtin_fmaf(h2b, w.y, dzB1);
                dzB2 = __builtin_fmaf(h2b, w.z, dzB2);
            }
            // combine q-halves across lane^32
            dzA0 += __shfl_xor(dzA0, 32, 64);  dzB0 += __shfl_xor(dzB0, 32, 64);
            dzA1 += __shfl_xor(dzA1, 32, 64);  dzB1 += __shfl_xor(dzB1, 32, 64);
            dzA2 += __shfl_xor(dzA2, 32, 64);  dzB2 += __shfl_xor(dzB2, 32, 64);
            fdA  += __shfl_xor(fdA, 32, 64);   fdB  += __shfl_xor(fdB, 32, 64);

            {   // lhi=0 lanes write sample l31 (sf0); lhi=1 lanes write 32+l31 (sf1)
                int s_w = lhi * 32 + l31;
                f32x4 o;
                o.x = lhi ? dzB0 : dzA0;
                o.y = lhi ? dzB1 : dzA1;
                o.z = lhi ? dzB2 : dzA2;
                o.w = lhi ? fdB  : fdA;
                *(f32x4*)&red[wid][s_w][0] = o;
            }
            __syncthreads();

            // ---- combine: k = [dz + bl, -trace]; RK4 update ----
            if (tid < TILE * 4) {
                int s = tid >> 2, c = tid & 3;
                float k = 0.f;
                #pragma unroll
                for (int qb = 0; qb < 16; ++qb) k += red[qb][s][c];
                k = (c < 3) ? (k + bll[c]) : (-k);
                float xsv = xss[s][c];
                if (stage == 0)      { kss[s][c] = k;          xcs[s][c] = xsv + 0.5f * hstp * k; }
                else if (stage == 1) { kss[s][c] += 2.f * k;   xcs[s][c] = xsv + 0.5f * hstp * k; }
                else if (stage == 2) { kss[s][c] += 2.f * k;   xcs[s][c] = xsv + hstp * k; }
                else {
                    float nx = xsv + (hstp / 6.f) * (kss[s][c] + k);
                    xss[s][c] = nx; xcs[s][c] = nx;
                }
            }
            __syncthreads();
        }
    }

    if (tid < TILE * 4) {
        int s = tid >> 2, c = tid & 3;
        out[(s0 + s) * 4 + c] = xss[s][c];
    }
}

extern "C" void kernel_launch(void* const* d_in, const int* in_sizes, int n_in,
                              void* d_out, int out_size, void* d_ws, size_t ws_size,
                              hipStream_t stream) {
    const float* states = (const float*)d_in[0];
    const float* W0 = (const float*)d_in[1];
    const float* b0 = (const float*)d_in[2];
    const float* W1 = (const float*)d_in[3];
    const float* b1 = (const float*)d_in[4];
    const float* Wl = (const float*)d_in[5];
    const float* bl = (const float*)d_in[6];
    float* out = (float*)d_out;

    __half* W1P = (__half*)d_ws;                 // 512*512 f16 = 512 KB
    __half* MP  = W1P + HD * HD;                 // +512 KB (total 1 MB)

    prep_kernel<<<(HD * HD) / 256, 256, 0, stream>>>(W1, W0, Wl, W1P, MP);

    const int B = in_sizes[0] / 4;               // 65536
    ode_kernel<<<B / TILE, NT, 0, stream>>>(states, W0, b0, b1, Wl, bl, W1P, MP, out);
}

// Round 12
// 443.763 us; speedup vs baseline: 215.4056x; 1.8324x over previous
//
#include <hip/hip_runtime.h>
#include <hip/hip_fp16.h>
#include <stdint.h>

#define HD 512
#define TILE 64
#define NSTEPS 1
#define NT 1024

typedef float    f32x16 __attribute__((ext_vector_type(16)));
typedef float    f32x4  __attribute__((ext_vector_type(4)));
typedef _Float16 f16x8  __attribute__((ext_vector_type(8)));

typedef __attribute__((address_space(3))) uint32_t lds_u32;
typedef __attribute__((address_space(1))) const uint32_t glb_u32;

__device__ __forceinline__ float tanh_fast(float x) {
    float e = __builtin_amdgcn_exp2f(x * 2.885390081777927f);   // e^{2x}
    return __builtin_fmaf(-2.f, __builtin_amdgcn_rcpf(1.f + e), 1.f);
}

// Packed fragment-ordered weights:
//   WP[idx], idx = ((qb*32 + kk)*64 + lane)*8 + j
//   value = W[p][q],  p = kk*16 + (lane>>5)*8 + j,  q = qb*32 + (lane&31)
__global__ void prep_kernel(const float* __restrict__ W1,
                            const float* __restrict__ W0,
                            const float* __restrict__ Wl,
                            __half* __restrict__ W1P,
                            __half* __restrict__ MP) {
    int idx = blockIdx.x * 256 + threadIdx.x;     // 0 .. 512*512-1
    int j    = idx & 7;
    int lane = (idx >> 3) & 63;
    int kk   = (idx >> 9) & 31;
    int qb   = idx >> 14;
    int p = kk * 16 + (lane >> 5) * 8 + j;
    int q = qb * 32 + (lane & 31);
    float w = W1[p * HD + q];
    float c = W0[HD + p]     * Wl[q * 3 + 0]
            + W0[2 * HD + p] * Wl[q * 3 + 1]
            + W0[3 * HD + p] * Wl[q * 3 + 2];
    W1P[idx] = __float2half(w);
    MP[idx]  = __float2half(w * c);
}

union U4 { uint4 q; f16x8 v; __half2 h[4]; uint32_t u[4]; };

__global__ __launch_bounds__(NT, 4)
void ode_kernel(const float* __restrict__ states,
                const float* __restrict__ W0,
                const float* __restrict__ b0,
                const float* __restrict__ b1,
                const float* __restrict__ Wl,
                const float* __restrict__ bl,
                const __half* __restrict__ W1P,
                const __half* __restrict__ MP,
                float* __restrict__ out) {
    __shared__ __half   h1s[TILE * HD];                 // 64 KB, 16-row swizzled
    __shared__ uint8_t  wbuf[2][16][2][1024];           // 64 KB weight DMA ring
    __shared__ __align__(16) float red[16][TILE][4];    // 16 KB [qb][s][{dz0,dz1,dz2,tr}]
    __shared__ __align__(16) float wlb[HD][4];          // 8 KB  {Wl0,Wl1,Wl2,b1}
    __shared__ __align__(16) float xcs[TILE][4], xss[TILE][4], kss[TILE][4];
    __shared__ float bll[4];

    const int tid  = threadIdx.x;
    const int lane = tid & 63;
    const int wid  = tid >> 6;        // 0..15 = qb
    const int l31  = lane & 31;
    const int lhi  = lane >> 5;       // 0/1
    const int s0   = blockIdx.x * TILE;

    // ---- one-time staging ----
    if (tid < 4) bll[tid] = (tid < 3) ? bl[tid] : 0.f;
    if (tid < HD) {
        f32x4 w;
        w.x = Wl[tid * 3 + 0]; w.y = Wl[tid * 3 + 1]; w.z = Wl[tid * 3 + 2];
        w.w = b1[tid];
        *(f32x4*)&wlb[tid][0] = w;
    }
    if (tid < TILE * 4) {
        int s = tid >> 2, c = tid & 3;
        float v = states[(s0 + s) * 4 + c];
        xss[s][c] = v;
        xcs[s][c] = v;
    }

    // ---- persistent preloads ----
    const int pa = (tid & 255) * 2;           // phase-A column pair
    const int sg = tid >> 8;                  // 0..3 sample group
    float w0r[8], b0r0, b0r1;
    #pragma unroll
    for (int a = 0; a < 4; ++a) {
        w0r[a * 2]     = W0[a * HD + pa];
        w0r[a * 2 + 1] = W0[a * HD + pa + 1];
    }
    b0r0 = b0[pa]; b0r1 = b0[pa + 1];

    // weight DMA sources (per-lane) and LDS ring bases (wave-uniform)
    const __half* w1src = W1P + wid * 16384 + lane * 8;
    const __half* msrc  = MP  + wid * 16384 + lane * 8;
    uint8_t* wb0 = &wbuf[0][wid][0][0];

    // prologue: slice 0 -> buf0, slice 1 -> buf1
    {
        __builtin_amdgcn_global_load_lds((glb_u32*)(w1src), (lds_u32*)(uintptr_t)(wb0), 16, 0, 0);
        __builtin_amdgcn_global_load_lds((glb_u32*)(msrc), (lds_u32*)(uintptr_t)(wb0 + 1024), 16, 0, 0);
        __builtin_amdgcn_global_load_lds((glb_u32*)(w1src + 512), (lds_u32*)(uintptr_t)(wb0 + 32768), 16, 0, 0);
        __builtin_amdgcn_global_load_lds((glb_u32*)(msrc + 512), (lds_u32*)(uintptr_t)(wb0 + 32768 + 1024), 16, 0, 0);
    }

    const int abase = l31 * HD + 8 * lhi;     // H-frag base (half elems), sample = l31
    const int aswz  = (l31 & 15) << 3;        // 16-row XOR swizzle (2-way max)
    const int wlbase = (wid * 32 + 4 * lhi);  // q base for phase C

    __syncthreads();

    const float hstp = 1.f / NSTEPS;
    const __half2 one2 = __floats2half2_rn(1.f, 1.f);

    for (int step = 0; step < NSTEPS; ++step) {
        float t0 = step * hstp;
        for (int stage = 0; stage < 4; ++stage) {
            float tEval = t0 + (stage == 0 ? 0.f : (stage == 3 ? hstp : 0.5f * hstp));

            // ---- phase A: h1 = tanh([t,x]@W0 + b0) -> f16 LDS (swizzled) ----
            #pragma unroll 4
            for (int it = 0; it < 16; ++it) {
                int s = it * 4 + sg;
                f32x4 xc = *(const f32x4*)&xcs[s][0];
                float a0 = b0r0 + tEval * w0r[0] + xc.x * w0r[2] + xc.y * w0r[4] + xc.z * w0r[6];
                float a1 = b0r1 + tEval * w0r[1] + xc.x * w0r[3] + xc.y * w0r[5] + xc.z * w0r[7];
                uint32_t pk = __builtin_bit_cast(uint32_t,
                    __builtin_amdgcn_cvt_pkrtz(tanh_fast(a0), tanh_fast(a1)));
                int elem = s * HD + pa;
                ((uint32_t*)h1s)[((elem ^ ((s & 15) << 3)) >> 1)] = pk;
            }
            __syncthreads();

            // ---- K-loop: accA = W1^T@H^T, accF = M^T@D^T; weights via LDS DMA ring ----
            f32x16 accA0 = {}, accA1 = {}, accF0 = {}, accF1 = {};

            #pragma unroll 4
            for (int kk = 0; kk < 32; ++kk) {
                const int buf = kk & 1;
                uint8_t* wbase = wb0 + buf * 32768;

                // slice kk resident when outstanding <= 2 (slice kk+1 in flight)
                asm volatile("s_waitcnt vmcnt(2)" ::: "memory");
                __builtin_amdgcn_sched_barrier(0);

                U4 wa, wm, H0, H1, D0, D1;
                wa.q = *(const uint4*)(wbase + lane * 16);
                wm.q = *(const uint4*)(wbase + 1024 + lane * 16);
                int a0 = (abase + kk * 16) ^ aswz;
                H0.q = *(const uint4*)(h1s + a0);
                H1.q = *(const uint4*)(h1s + a0 + 32 * HD);

                // ds_reads retired -> safe to overwrite this buf with slice kk+2
                asm volatile("s_waitcnt lgkmcnt(0)" ::: "memory");
                __builtin_amdgcn_sched_barrier(0);
                {
                    int nk = (kk + 2) & 31;
                    __builtin_amdgcn_global_load_lds((glb_u32*)(w1src + nk * 512),
                        (lds_u32*)(uintptr_t)(wbase), 16, 0, 0);
                    __builtin_amdgcn_global_load_lds((glb_u32*)(msrc + nk * 512),
                        (lds_u32*)(uintptr_t)(wbase + 1024), 16, 0, 0);
                }

                #pragma unroll
                for (int i = 0; i < 4; ++i) {
                    D0.h[i] = __hfma2(__hneg2(H0.h[i]), H0.h[i], one2);   // 1 - h^2
                    D1.h[i] = __hfma2(__hneg2(H1.h[i]), H1.h[i], one2);
                }
                __builtin_amdgcn_s_setprio(1);
                accA0 = __builtin_amdgcn_mfma_f32_32x32x16_f16(wa.v, H0.v, accA0, 0, 0, 0);
                accF0 = __builtin_amdgcn_mfma_f32_32x32x16_f16(wm.v, D0.v, accF0, 0, 0, 0);
                accA1 = __builtin_amdgcn_mfma_f32_32x32x16_f16(wa.v, H1.v, accA1, 0, 0, 0);
                accF1 = __builtin_amdgcn_mfma_f32_32x32x16_f16(wm.v, D1.v, accF1, 0, 0, 0);
                __builtin_amdgcn_s_setprio(0);
            }

            // ---- phase C: h2/d2 per q-row; in-lane q-reduction ----
            float dzA0 = 0.f, dzA1 = 0.f, dzA2 = 0.f, fdA = 0.f;   // sf0
            float dzB0 = 0.f, dzB1 = 0.f, dzB2 = 0.f, fdB = 0.f;   // sf1
            #pragma unroll
            for (int r = 0; r < 16; ++r) {
                f32x4 w = *(const f32x4*)&wlb[wlbase + (r & 3) + 8 * (r >> 2)][0];
                float h2a = tanh_fast(accA0[r] + w.w);
                float h2b = tanh_fast(accA1[r] + w.w);
                float d2a = __builtin_fmaf(-h2a, h2a, 1.f);
                float d2b = __builtin_fmaf(-h2b, h2b, 1.f);
                fdA  = __builtin_fmaf(accF0[r], d2a, fdA);
                fdB  = __builtin_fmaf(accF1[r], d2b, fdB);
                dzA0 = __builtin_fmaf(h2a, w.x, dzA0);
                dzA1 = __builtin_fmaf(h2a, w.y, dzA1);
                dzA2 = __builtin_fmaf(h2a, w.z, dzA2);
                dzB0 = __builtin_fmaf(h2b, w.x, dzB0);
                dzB1 = __builtin_fmaf(h2b, w.y, dzB1);
                dzB2 = __builtin_fmaf(h2b, w.z, dzB2);
            }
            // combine q-halves across lane^32
            dzA0 += __shfl_xor(dzA0, 32, 64);  dzB0 += __shfl_xor(dzB0, 32, 64);
            dzA1 += __shfl_xor(dzA1, 32, 64);  dzB1 += __shfl_xor(dzB1, 32, 64);
            dzA2 += __shfl_xor(dzA2, 32, 64);  dzB2 += __shfl_xor(dzB2, 32, 64);
            fdA  += __shfl_xor(fdA, 32, 64);   fdB  += __shfl_xor(fdB, 32, 64);

            {   // lhi=0 lanes write sample l31 (sf0); lhi=1 lanes write 32+l31 (sf1)
                int s_w = lhi * 32 + l31;
                f32x4 o;
                o.x = lhi ? dzB0 : dzA0;
                o.y = lhi ? dzB1 : dzA1;
                o.z = lhi ? dzB2 : dzA2;
                o.w = lhi ? fdB  : fdA;
                *(f32x4*)&red[wid][s_w][0] = o;
            }
            __syncthreads();

            // ---- combine: k = [dz + bl, -trace]; RK4 update ----
            if (tid < TILE * 4) {
                int s = tid >> 2, c = tid & 3;
                float k = 0.f;
                #pragma unroll
                for (int qb = 0; qb < 16; ++qb) k += red[qb][s][c];
                k = (c < 3) ? (k + bll[c]) : (-k);
                float xsv = xss[s][c];
                if (stage == 0)      { kss[s][c] = k;          xcs[s][c] = xsv + 0.5f * hstp * k; }
                else if (stage == 1) { kss[s][c] += 2.f * k;   xcs[s][c] = xsv + 0.5f * hstp * k; }
                else if (stage == 2) { kss[s][c] += 2.f * k;   xcs[s][c] = xsv + hstp * k; }
                else {
                    float nx = xsv + (hstp / 6.f) * (kss[s][c] + k);
                    xss[s][c] = nx; xcs[s][c] = nx;
                }
            }
            __syncthreads();
        }
    }

    if (tid < TILE * 4) {
        int s = tid >> 2, c = tid & 3;
        out[(s0 + s) * 4 + c] = xss[s][c];
    }
}

extern "C" void kernel_launch(void* const* d_in, const int* in_sizes, int n_in,
                              void* d_out, int out_size, void* d_ws, size_t ws_size,
                              hipStream_t stream) {
    const float* states = (const float*)d_in[0];
    const float* W0 = (const float*)d_in[1];
    const float* b0 = (const float*)d_in[2];
    const float* W1 = (const float*)d_in[3];
    const float* b1 = (const float*)d_in[4];
    const float* Wl = (const float*)d_in[5];
    const float* bl = (const float*)d_in[6];
    float* out = (float*)d_out;

    __half* W1P = (__half*)d_ws;                 // 512*512 f16 = 512 KB
    __half* MP  = W1P + HD * HD;                 // +512 KB (total 1 MB)

    prep_kernel<<<(HD * HD) / 256, 256, 0, stream>>>(W1, W0, Wl, W1P, MP);

    const int B = in_sizes[0] / 4;               // 65536
    ode_kernel<<<B / TILE, NT, 0, stream>>>(states, W0, b0, b1, Wl, bl, W1P, MP, out);
}

// Round 14
// 430.943 us; speedup vs baseline: 221.8134x; 1.0297x over previous
//
#include <hip/hip_runtime.h>
#include <hip/hip_fp16.h>
#include <stdint.h>

#define HD 512
#define TILE 64
#define NSTEPS 1
#define NT 1024

typedef float    f32x16 __attribute__((ext_vector_type(16)));
typedef float    f32x4  __attribute__((ext_vector_type(4)));
typedef _Float16 f16x8  __attribute__((ext_vector_type(8)));

typedef __attribute__((address_space(3))) uint32_t lds_u32;
typedef __attribute__((address_space(1))) const uint32_t glb_u32;

__device__ __forceinline__ float tanh_fast(float x) {
    float e = __builtin_amdgcn_exp2f(x * 2.885390081777927f);   // e^{2x}
    return __builtin_fmaf(-2.f, __builtin_amdgcn_rcpf(1.f + e), 1.f);
}

__device__ __forceinline__ uint32_t pkh(float lo, float hi) {
    return __builtin_bit_cast(uint32_t, __builtin_amdgcn_cvt_pkrtz(lo, hi));
}

// Packed fragment-ordered weights:
//   WP[idx], idx = ((qb*32 + kk)*64 + lane)*8 + j
//   value = W[p][q],  p = kk*16 + (lane>>5)*8 + j,  q = qb*32 + (lane&31)
__global__ void prep_kernel(const float* __restrict__ W1,
                            const float* __restrict__ W0,
                            const float* __restrict__ Wl,
                            __half* __restrict__ W1P,
                            __half* __restrict__ MP) {
    int idx = blockIdx.x * 256 + threadIdx.x;     // 0 .. 512*512-1
    int j    = idx & 7;
    int lane = (idx >> 3) & 63;
    int kk   = (idx >> 9) & 31;
    int qb   = idx >> 14;
    int p = kk * 16 + (lane >> 5) * 8 + j;
    int q = qb * 32 + (lane & 31);
    float w = W1[p * HD + q];
    float c = W0[HD + p]     * Wl[q * 3 + 0]
            + W0[2 * HD + p] * Wl[q * 3 + 1]
            + W0[3 * HD + p] * Wl[q * 3 + 2];
    W1P[idx] = __float2half(w);
    MP[idx]  = __float2half(w * c);
}

union U4 { uint4 q; f16x8 v; __half2 h[4]; uint32_t u[4]; };

__global__ __launch_bounds__(NT, 4)
void ode_kernel(const float* __restrict__ states,
                const float* __restrict__ W0,
                const float* __restrict__ b0,
                const float* __restrict__ b1,
                const float* __restrict__ Wl,
                const float* __restrict__ bl,
                const __half* __restrict__ W1P,
                const __half* __restrict__ MP,
                float* __restrict__ out) {
    __shared__ __half   h1s[TILE * HD];                 // 64 KB, 16-row swizzled
    __shared__ uint8_t  wbuf[2][16][2][1024];           // 64 KB weight DMA ring
    __shared__ __align__(16) float red[16][TILE][4];    // 16 KB [qb][s][{dz0,dz1,dz2,tr}]
    __shared__ __align__(16) float wlb[HD][4];          // 8 KB  {Wl0,Wl1,Wl2,b1}
    __shared__ __align__(16) float xcs[TILE][4], xss[TILE][4], kss[TILE][4];
    __shared__ float bll[4];

    const int tid  = threadIdx.x;
    const int lane = tid & 63;
    const int wid  = tid >> 6;        // 0..15 = qb (K-loop) = p-tile (phase A)
    const int l31  = lane & 31;
    const int lhi  = lane >> 5;       // 0/1
    const int s0   = blockIdx.x * TILE;

    // ---- one-time staging ----
    if (tid < 4) bll[tid] = (tid < 3) ? bl[tid] : 0.f;
    if (tid < HD) {
        f32x4 w;
        w.x = Wl[tid * 3 + 0]; w.y = Wl[tid * 3 + 1]; w.z = Wl[tid * 3 + 2];
        w.w = b1[tid];
        *(f32x4*)&wlb[tid][0] = w;
    }
    if (tid < TILE * 4) {
        int s = tid >> 2, c = tid & 3;
        float v = states[(s0 + s) * 4 + c];
        xss[s][c] = v;
        xcs[s][c] = v;
    }

    // ---- persistent phase-A W0 fragment (A-operand, per-wave p-tile) ----
    // A[p][k] = W0ext[k][wid*32+p]; W0ext rows: k=0 -> b0, k=1 -> W0[t], k=2..4 -> W0[x], else 0
    U4 w0f;
    {
        int p = wid * 32 + l31;
        float v0 = b0[p];
        float v1 = W0[p];
        float v2 = W0[HD + p];
        float v3 = W0[2 * HD + p];
        float v4 = W0[3 * HD + p];
        w0f.u[0] = lhi ? 0u : pkh(v0, v1);
        w0f.u[1] = lhi ? 0u : pkh(v2, v3);
        w0f.u[2] = lhi ? 0u : pkh(v4, 0.f);
        w0f.u[3] = 0u;
    }

    // weight DMA sources (per-lane) and LDS ring bases (wave-uniform)
    const __half* w1src = W1P + wid * 16384 + lane * 8;
    const __half* msrc  = MP  + wid * 16384 + lane * 8;
    uint8_t* wb0 = &wbuf[0][wid][0][0];

    // prologue: slice 0 -> buf0, slice 1 -> buf1
    {
        __builtin_amdgcn_global_load_lds((glb_u32*)(w1src), (lds_u32*)(uintptr_t)(wb0), 16, 0, 0);
        __builtin_amdgcn_global_load_lds((glb_u32*)(msrc), (lds_u32*)(uintptr_t)(wb0 + 1024), 16, 0, 0);
        __builtin_amdgcn_global_load_lds((glb_u32*)(w1src + 512), (lds_u32*)(uintptr_t)(wb0 + 32768), 16, 0, 0);
        __builtin_amdgcn_global_load_lds((glb_u32*)(msrc + 512), (lds_u32*)(uintptr_t)(wb0 + 32768 + 1024), 16, 0, 0);
    }

    const int abase = l31 * HD + 8 * lhi;     // H-frag base (half elems), sample = l31
    const int aswz  = (l31 & 15) << 3;        // 16-row XOR swizzle (2-way max)
    const int wlbase = (wid * 32 + 4 * lhi);  // q base for phase C

    // phase-A write bases: frag0 sample = l31, frag1 sample = 32+l31; p-rows = wid*32+4*lhi+poff
    const int eb0 = l31 * HD + wid * 32 + 4 * lhi;
    const int eb1 = (32 + l31) * HD + wid * 32 + 4 * lhi;

    __syncthreads();

    const float hstp = 1.f / NSTEPS;
    const __half2 one2 = __floats2half2_rn(1.f, 1.f);

    for (int step = 0; step < NSTEPS; ++step) {
        float t0 = step * hstp;
        for (int stage = 0; stage < 4; ++stage) {
            float tEval = t0 + (stage == 0 ? 0.f : (stage == 3 ? hstp : 0.5f * hstp));

            // ---- phase A (MFMA): H1 = tanh(W0ext^T @ Z^T), Z = [1,t,x0,x1,x2,0..] ----
            {
                f32x4 xc0 = *(const f32x4*)&xcs[l31][0];
                f32x4 xc1 = *(const f32x4*)&xcs[32 + l31][0];
                uint32_t bt = pkh(1.f, tEval);
                U4 bf0, bf1;
                bf0.u[0] = lhi ? 0u : bt;
                bf0.u[1] = lhi ? 0u : pkh(xc0.x, xc0.y);
                bf0.u[2] = lhi ? 0u : pkh(xc0.z, 0.f);
                bf0.u[3] = 0u;
                bf1.u[0] = lhi ? 0u : bt;
                bf1.u[1] = lhi ? 0u : pkh(xc1.x, xc1.y);
                bf1.u[2] = lhi ? 0u : pkh(xc1.z, 0.f);
                bf1.u[3] = 0u;
                f32x16 aH0 = {}, aH1 = {};
                aH0 = __builtin_amdgcn_mfma_f32_32x32x16_f16(w0f.v, bf0.v, aH0, 0, 0, 0);
                aH1 = __builtin_amdgcn_mfma_f32_32x32x16_f16(w0f.v, bf1.v, aH1, 0, 0, 0);
                #pragma unroll
                for (int pr = 0; pr < 8; ++pr) {
                    int r = pr * 2;
                    int poff = (r & 3) + 8 * (r >> 2);   // 0,2,8,10,16,18,24,26
                    uint32_t pk0 = pkh(tanh_fast(aH0[r]), tanh_fast(aH0[r + 1]));
                    uint32_t pk1 = pkh(tanh_fast(aH1[r]), tanh_fast(aH1[r + 1]));
                    ((uint32_t*)h1s)[((eb0 + poff) ^ aswz) >> 1] = pk0;
                    ((uint32_t*)h1s)[((eb1 + poff) ^ aswz) >> 1] = pk1;
                }
            }
            __syncthreads();

            // ---- K-loop: accA = W1^T@H^T, accF = M^T@D^T; weights via LDS DMA ring ----
            f32x16 accA0 = {}, accA1 = {}, accF0 = {}, accF1 = {};

            #pragma unroll 4
            for (int kk = 0; kk < 32; ++kk) {
                const int buf = kk & 1;
                uint8_t* wbase = wb0 + buf * 32768;

                // slice kk resident when outstanding <= 2 (slice kk+1 in flight)
                asm volatile("s_waitcnt vmcnt(2)" ::: "memory");
                __builtin_amdgcn_sched_barrier(0);

                U4 wa, wm, H0, H1, D0, D1;
                wa.q = *(const uint4*)(wbase + lane * 16);
                wm.q = *(const uint4*)(wbase + 1024 + lane * 16);
                int a0 = (abase + kk * 16) ^ aswz;
                H0.q = *(const uint4*)(h1s + a0);
                H1.q = *(const uint4*)(h1s + a0 + 32 * HD);

                // ds_reads retired -> safe to overwrite this buf with slice kk+2
                asm volatile("s_waitcnt lgkmcnt(0)" ::: "memory");
                __builtin_amdgcn_sched_barrier(0);
                {
                    int nk = (kk + 2) & 31;
                    __builtin_amdgcn_global_load_lds((glb_u32*)(w1src + nk * 512),
                        (lds_u32*)(uintptr_t)(wbase), 16, 0, 0);
                    __builtin_amdgcn_global_load_lds((glb_u32*)(msrc + nk * 512),
                        (lds_u32*)(uintptr_t)(wbase + 1024), 16, 0, 0);
                }

                #pragma unroll
                for (int i = 0; i < 4; ++i) {
                    D0.h[i] = __hfma2(__hneg2(H0.h[i]), H0.h[i], one2);   // 1 - h^2
                    D1.h[i] = __hfma2(__hneg2(H1.h[i]), H1.h[i], one2);
                }
                __builtin_amdgcn_s_setprio(1);
                accA0 = __builtin_amdgcn_mfma_f32_32x32x16_f16(wa.v, H0.v, accA0, 0, 0, 0);
                accF0 = __builtin_amdgcn_mfma_f32_32x32x16_f16(wm.v, D0.v, accF0, 0, 0, 0);
                accA1 = __builtin_amdgcn_mfma_f32_32x32x16_f16(wa.v, H1.v, accA1, 0, 0, 0);
                accF1 = __builtin_amdgcn_mfma_f32_32x32x16_f16(wm.v, D1.v, accF1, 0, 0, 0);
                __builtin_amdgcn_s_setprio(0);
            }

            // ---- phase C: h2/d2 per q-row; in-lane q-reduction ----
            float dzA0 = 0.f, dzA1 = 0.f, dzA2 = 0.f, fdA = 0.f;   // sf0
            float dzB0 = 0.f, dzB1 = 0.f, dzB2 = 0.f, fdB = 0.f;   // sf1
            #pragma unroll
            for (int r = 0; r < 16; ++r) {
                f32x4 w = *(const f32x4*)&wlb[wlbase + (r & 3) + 8 * (r >> 2)][0];
                float h2a = tanh_fast(accA0[r] + w.w);
                float h2b = tanh_fast(accA1[r] + w.w);
                float d2a = __builtin_fmaf(-h2a, h2a, 1.f);
                float d2b = __builtin_fmaf(-h2b, h2b, 1.f);
                fdA  = __builtin_fmaf(accF0[r], d2a, fdA);
                fdB  = __builtin_fmaf(accF1[r], d2b, fdB);
                dzA0 = __builtin_fmaf(h2a, w.x, dzA0);
                dzA1 = __builtin_fmaf(h2a, w.y, dzA1);
                dzA2 = __builtin_fmaf(h2a, w.z, dzA2);
                dzB0 = __builtin_fmaf(h2b, w.x, dzB0);
                dzB1 = __builtin_fmaf(h2b, w.y, dzB1);
                dzB2 = __builtin_fmaf(h2b, w.z, dzB2);
            }
            // combine q-halves across lane^32
            dzA0 += __shfl_xor(dzA0, 32, 64);  dzB0 += __shfl_xor(dzB0, 32, 64);
            dzA1 += __shfl_xor(dzA1, 32, 64);  dzB1 += __shfl_xor(dzB1, 32, 64);
            dzA2 += __shfl_xor(dzA2, 32, 64);  dzB2 += __shfl_xor(dzB2, 32, 64);
            fdA  += __shfl_xor(fdA, 32, 64);   fdB  += __shfl_xor(fdB, 32, 64);

            {   // lhi=0 lanes write sample l31 (sf0); lhi=1 lanes write 32+l31 (sf1)
                int s_w = lhi * 32 + l31;
                f32x4 o;
                o.x = lhi ? dzB0 : dzA0;
                o.y = lhi ? dzB1 : dzA1;
                o.z = lhi ? dzB2 : dzA2;
                o.w = lhi ? fdB  : fdA;
                *(f32x4*)&red[wid][s_w][0] = o;
            }
            __syncthreads();

            // ---- combine: k = [dz + bl, -trace]; RK4 update ----
            if (tid < TILE * 4) {
                int s = tid >> 2, c = tid & 3;
                float k = 0.f;
                #pragma unroll
                for (int qb = 0; qb < 16; ++qb) k += red[qb][s][c];
                k = (c < 3) ? (k + bll[c]) : (-k);
                float xsv = xss[s][c];
                if (stage == 0)      { kss[s][c] = k;          xcs[s][c] = xsv + 0.5f * hstp * k; }
                else if (stage == 1) { kss[s][c] += 2.f * k;   xcs[s][c] = xsv + 0.5f * hstp * k; }
                else if (stage == 2) { kss[s][c] += 2.f * k;   xcs[s][c] = xsv + hstp * k; }
                else {
                    float nx = xsv + (hstp / 6.f) * (kss[s][c] + k);
                    xss[s][c] = nx; xcs[s][c] = nx;
                }
            }
            __syncthreads();
        }
    }

    if (tid < TILE * 4) {
        int s = tid >> 2, c = tid & 3;
        out[(s0 + s) * 4 + c] = xss[s][c];
    }
}

extern "C" void kernel_launch(void* const* d_in, const int* in_sizes, int n_in,
                              void* d_out, int out_size, void* d_ws, size_t ws_size,
                              hipStream_t stream) {
    const float* states = (const float*)d_in[0];
    const float* W0 = (const float*)d_in[1];
    const float* b0 = (const float*)d_in[2];
    const float* W1 = (const float*)d_in[3];
    const float* b1 = (const float*)d_in[4];
    const float* Wl = (const float*)d_in[5];
    const float* bl = (const float*)d_in[6];
    float* out = (float*)d_out;

    __half* W1P = (__half*)d_ws;                 // 512*512 f16 = 512 KB
    __half* MP  = W1P + HD * HD;                 // +512 KB (total 1 MB)

    prep_kernel<<<(HD * HD) / 256, 256, 0, stream>>>(W1, W0, Wl, W1P, MP);

    const int B = in_sizes[0] / 4;               // 65536
    ode_kernel<<<B / TILE, NT, 0, stream>>>(states, W0, b0, b1, Wl, bl, W1P, MP, out);
}